// Round 3
// baseline (1054.117 us; speedup 1.0000x reference)
//
#include <hip/hip_runtime.h>
#include <hip/hip_bf16.h>
#include <cstdint>
#include <cstddef>

typedef __hip_bfloat16 bf16;
typedef short v8s __attribute__((ext_vector_type(8)));
typedef float v4f __attribute__((ext_vector_type(4)));
typedef unsigned short v8u __attribute__((ext_vector_type(8)));
typedef unsigned short v4u __attribute__((ext_vector_type(4)));
typedef unsigned short v2u __attribute__((ext_vector_type(2)));

#define N_NODES 50000
#define N_HE    5000
#define N_EDGE  800000
#define N_INC   400000
#define W_TOTAL 456704
#define NBREL   275   // 98 adj + 79 heg + 98 hng bucket cursors

#define AS1CV const __attribute__((address_space(1))) void*
#define AS3V  __attribute__((address_space(3))) void*

__device__ inline float bfh(uint32_t u) { return __uint_as_float(u << 16); }
__device__ inline uint16_t rne16(float f) {
  uint32_t u = __float_as_uint(f);
  return (uint16_t)((u + 0x7FFFu + ((u >> 16) & 1u)) >> 16);
}

// ---- prep: zero gcnt+brel + split weights (incl lpw, stride 96) + cvt x
// F=256 weight matrices are stored CHUNK-MAJOR + XOR-swizzled so that
// global_load_lds linear writes produce a bank-conflict-free LDS layout:
//   element w[row][c*32 + q*8 + e] -> idx c*8192 + row*32 + ((q^(row&3))<<3) + e
// F=40 matrices (s2wl/s2wr/h4w) stay row-major (old LDS path).
__global__ void prep_kernel(int* gcnt, int* brel,
                            const float* s0wl, const float* s0wr,
                            const float* s1wl, const float* s1wr,
                            const float* s2wl, const float* s2wr,
                            const float* h0w, const float* h1w,
                            const float* h2w, const float* h3w, const float* h4w,
                            uint16_t* hi, uint16_t* lo,
                            const float* lpw, uint16_t* lpWh, uint16_t* lpWl,
                            const float* X, uint16_t* XB) {
  int b = blockIdx.x;
  if (b < 3) {
    int i = b * 256 + threadIdx.x;
    if (i < NBREL) gcnt[i] = 0;
    else if (i < 2 * NBREL) brel[i - NBREL] = 0;
    return;
  }
  if (b < 1787) {
    int i = (b - 3) * 256 + threadIdx.x;
    if (i >= W_TOTAL) return;
    const float* src; int base; int kln2; int sw;
    if (i < 32768)       { src = s0wl; base = 0;      kln2 = 7; sw = 1; }
    else if (i < 65536)  { src = s0wr; base = 32768;  kln2 = 7; sw = 1; }
    else if (i < 131072) { src = s1wl; base = 65536;  kln2 = 8; sw = 1; }
    else if (i < 196608) { src = s1wr; base = 131072; kln2 = 8; sw = 1; }
    else if (i < 206848) { src = s2wl; base = 196608; kln2 = 8; sw = 0; }
    else if (i < 217088) { src = s2wr; base = 206848; kln2 = 8; sw = 0; }
    else if (i < 249856) { src = h0w;  base = 217088; kln2 = 7; sw = 1; }
    else if (i < 315392) { src = h1w;  base = 249856; kln2 = 8; sw = 1; }
    else if (i < 380928) { src = h2w;  base = 315392; kln2 = 8; sw = 1; }
    else if (i < 446464) { src = h3w;  base = 380928; kln2 = 8; sw = 1; }
    else                 { src = h4w;  base = 446464; kln2 = 8; sw = 0; }
    int j = i - base;
    float v = src[j];
    int nj = j;
    if (sw) {
      int row = j >> kln2;
      int col = j & ((1 << kln2) - 1);
      int c = col >> 5, qq = (col >> 3) & 3, e = col & 7;
      nj = c * 8192 + row * 32 + ((qq ^ (row & 3)) << 3) + e;
    }
    uint16_t hb = rne16(v);
    hi[base + nj] = hb;
    lo[base + nj] = rne16(v - bfh(hb));
    return;
  }
  if (b < 1802) {
    int i = (b - 1787) * 256 + threadIdx.x;   // 40 rows x 96 cols
    if (i >= 40 * 96) return;
    int row = i / 96, col = i - row * 96;
    float v = (col < 80) ? lpw[row * 80 + col] : 0.f;
    uint16_t hb = rne16(v);
    lpWh[i] = hb;
    lpWl[i] = rne16(v - bfh(hb));
    return;
  }
  {
    int i = (b - 1802) * 256 + threadIdx.x;   // v4 index
    if (i >= N_NODES * 32) return;
    v4f v = *((const v4f*)X + i);
    v4u o;
    o[0] = rne16(v[0]); o[1] = rne16(v[1]); o[2] = rne16(v[2]); o[3] = rne16(v[3]);
    *((v4u*)XB + i) = o;
  }
}

// ---------------- bucket-level histogram (LDS-local; replaces hist_kernel)
template <int NB, int SH>
__device__ inline void bhist_section(const int* __restrict__ key_arr, int n, int blk,
                                     int* __restrict__ gcnt) {
  __shared__ int h[128];
  int t = threadIdx.x;
  for (int k = t; k < NB; k += 256) h[k] = 0;
  __syncthreads();
  int e0 = blk * 4096;
  int cnt = min(4096, n - e0);
  for (int k = t; k < cnt; k += 256) atomicAdd(&h[key_arr[e0 + k] >> SH], 1);
  __syncthreads();
  for (int k = t; k < NB; k += 256) atomicAdd(&gcnt[k], h[k]);
}

__global__ __launch_bounds__(256) void bhist_kernel(
    const int* __restrict__ dst, const int* __restrict__ he_edge,
    const int* __restrict__ he_node, int* gcnt) {
  int b = blockIdx.x;
  if (b < 196)      bhist_section<98, 9>(dst, N_EDGE, b, gcnt);
  else if (b < 294) bhist_section<79, 6>(he_edge, N_INC, b - 196, gcnt + 98);
  else              bhist_section<98, 9>(he_node, N_INC, b - 294, gcnt + 177);
}

// ---------------- bucket-base scan (one wave per section) + CSR sentinels
__global__ void bscan_kernel(const int* __restrict__ gcnt, int* gbb,
                             int* adj_off, int* heg_off, int* hng_off) {
  int t = threadIdx.x;
  if (t == 0)        { int s = 0; for (int b = 0; b < 98; ++b) { gbb[b] = s; s += gcnt[b]; } gbb[98] = s; }
  else if (t == 64)  { int s = 0; for (int b = 0; b < 79; ++b) { gbb[99 + b] = s; s += gcnt[98 + b]; } gbb[99 + 79] = s; }
  else if (t == 128) { int s = 0; for (int b = 0; b < 98; ++b) { gbb[179 + b] = s; s += gcnt[177 + b]; } gbb[179 + 98] = s; }
  else if (t == 192) { adj_off[N_NODES] = N_EDGE; heg_off[N_HE] = N_INC; hng_off[N_NODES] = N_INC; }
}

// ---------------- binned two-phase fill (no scatter write amplification)
template <int NB, int SH>
__device__ inline void binA_section(const int* __restrict__ key_arr,
                                    const int* __restrict__ pay_arr, int n, int blk,
                                    const int* __restrict__ bb,
                                    int* brel, uint32_t* __restrict__ stg) {
  __shared__ int lcnt[128], lscan[128], lcnt2[128], gbase[128];
  __shared__ uint32_t sstage[4096];
  int t = threadIdx.x;
  int e0 = blk * 4096;
  int cnt = min(4096, n - e0);
  for (int k = t; k < NB; k += 256) { lcnt[k] = 0; lcnt2[k] = 0; }
  __syncthreads();
  for (int k = t; k < cnt; k += 256) atomicAdd(&lcnt[key_arr[e0 + k] >> SH], 1);
  __syncthreads();
  if (t == 0) {
    int s = 0;
    for (int b = 0; b < NB; ++b) { lscan[b] = s; s += lcnt[b]; }
  }
  __syncthreads();
  if (t < NB) gbase[t] = bb[t] + atomicAdd(&brel[t], lcnt[t]);
  __syncthreads();
  for (int k = t; k < cnt; k += 256) {
    int key = key_arr[e0 + k];
    int pay = pay_arr[e0 + k];
    int b = key >> SH;
    int r = atomicAdd(&lcnt2[b], 1);
    sstage[lscan[b] + r] = ((uint32_t)pay << 16) | (uint32_t)key;
  }
  __syncthreads();
  for (int b = 0; b < NB; ++b) {
    int len = lcnt[b], ls = lscan[b], gb = gbase[b];
    for (int k = t; k < len; k += 256) stg[gb + k] = sstage[ls + k];
  }
}

__global__ __launch_bounds__(256) void binA_kernel(
    const int* __restrict__ src, const int* __restrict__ dst,
    const int* __restrict__ he_node, const int* __restrict__ he_edge,
    const int* __restrict__ gbb, int* brel,
    uint32_t* stg_adj, uint32_t* stg_heg, uint32_t* stg_hng) {
  int b = blockIdx.x;
  if (b < 196)      binA_section<98, 9>(dst, src, N_EDGE, b, gbb, brel, stg_adj);
  else if (b < 294) binA_section<79, 6>(he_edge, he_node, N_INC, b - 196, gbb + 99, brel + 98, stg_heg);
  else              binA_section<98, 9>(he_node, he_edge, N_INC, b - 294, gbb + 179, brel + 177, stg_hng);
}

// Pass B + per-node count/scan: writes CSR offsets, reciprocal scales, payloads.
template <int BS, int SH, int MODE>
__device__ inline void binB2_section(int bkt, const int* __restrict__ bb, int nkeys,
                                     const uint32_t* __restrict__ stg,
                                     int* __restrict__ off_out,
                                     float* __restrict__ scl,
                                     uint16_t* __restrict__ out) {
  __shared__ int lcnt[512], loff[512], lcur[512];
  __shared__ int ws[4];
  int t = threadIdx.x;
  int nb0 = bkt << SH;
  int nb1 = min(nb0 + BS, nkeys);
  int nn = nb1 - nb0;
  int e0 = bb[bkt], e1 = bb[bkt + 1];
  for (int k = t; k < nn; k += 256) lcnt[k] = 0;
  __syncthreads();
  for (int e = e0 + t; e < e1; e += 256)
    atomicAdd(&lcnt[(int)(stg[e] & 0xFFFFu) - nb0], 1);
  __syncthreads();
  // exclusive scan over nn counts (2 per thread, shfl within wave, 4 waves)
  int lane = t & 63, wv = t >> 6;
  int i0 = 2 * t;
  int a0 = (i0 < nn) ? lcnt[i0] : 0;
  int a1 = (i0 + 1 < nn) ? lcnt[i0 + 1] : 0;
  int ts = a0 + a1;
  int val = ts;
#pragma unroll
  for (int d = 1; d < 64; d <<= 1) {
    int x = __shfl_up(val, d);
    if (lane >= d) val += x;
  }
  if (lane == 63) ws[wv] = val;
  __syncthreads();
  if (t == 0) {
    int s = 0;
#pragma unroll
    for (int w = 0; w < 4; ++w) { int v = ws[w]; ws[w] = s; s += v; }
  }
  __syncthreads();
  int excl = ws[wv] + (val - ts);
  if (i0 < nn) loff[i0] = excl;
  if (i0 + 1 < nn) loff[i0 + 1] = excl + a0;
  __syncthreads();
  for (int k = t; k < nn; k += 256) {
    int base = e0 + loff[k];
    off_out[nb0 + k] = base;
    lcur[k] = base;
    int c = lcnt[k];
    scl[nb0 + k] = (MODE == 0) ? 1.0f / (float)(c > 1 ? c : 1)
                               : (c > 0 ? 1.0f / (float)c : 0.f);
  }
  __syncthreads();
  for (int e = e0 + t; e < e1; e += 256) {
    uint32_t v = stg[e];
    int key = (int)(v & 0xFFFFu);
    int p = atomicAdd(&lcur[key - nb0], 1);
    out[p] = (uint16_t)(v >> 16);
  }
}

__global__ __launch_bounds__(256) void binB2_kernel(
    const int* __restrict__ gbb,
    const uint32_t* __restrict__ stg_adj, const uint32_t* __restrict__ stg_heg,
    const uint32_t* __restrict__ stg_hng,
    int* adj_off, int* heg_off, int* hng_off,
    float* deg_inv, float* binv, float* dinv,
    uint16_t* adj_src, uint16_t* heg_node, uint16_t* hng_edge) {
  int b = blockIdx.x;
  if (b < 98)       binB2_section<512, 9, 0>(b, gbb, N_NODES, stg_adj, adj_off, deg_inv, adj_src);
  else if (b < 177) binB2_section<64, 6, 1>(b - 98, gbb + 99, N_HE, stg_heg, heg_off, binv, heg_node);
  else              binB2_section<512, 9, 1>(b - 177, gbb + 179, N_NODES, stg_hng, hng_off, dinv, hng_edge);
}

// ------------------------------- gather-mean row body (uint16 CSR idx)
template <int F>
__device__ inline void agg_row(const int* __restrict__ off, const uint16_t* __restrict__ idx,
                               const float* __restrict__ scale,
                               const uint16_t* __restrict__ X,
                               uint16_t* __restrict__ OUT, int row,
                               const float* __restrict__ bias, int do_relu) {
  constexpr int VEC = (F >= 256) ? 4 : 2;
  int t = threadIdx.x;
  if (t * VEC >= F) return;
  int j0 = off[row], j1 = off[row + 1];
  float sc = scale[row];
  float acc[VEC];
#pragma unroll
  for (int k = 0; k < VEC; ++k) acc[k] = 0.f;

  int j = j0;
  for (; j + 7 < j1; j += 8) {
    int s[8];
#pragma unroll
    for (int u = 0; u < 8; ++u) s[u] = idx[j + u];
    if (VEC == 4) {
      v4u v[8];
#pragma unroll
      for (int u = 0; u < 8; ++u) v[u] = *(const v4u*)(X + (size_t)s[u] * F + t * 4);
#pragma unroll
      for (int u = 0; u < 8; ++u)
#pragma unroll
        for (int k = 0; k < 4; ++k) acc[k] += bfh(v[u][k]);
    } else {
      v2u v[8];
#pragma unroll
      for (int u = 0; u < 8; ++u) v[u] = *(const v2u*)(X + (size_t)s[u] * F + t * 2);
#pragma unroll
      for (int u = 0; u < 8; ++u)
#pragma unroll
        for (int k = 0; k < 2; ++k) acc[k] += bfh(v[u][k]);
    }
  }
  for (; j < j1; ++j) {
    int s = idx[j];
    if (VEC == 4) {
      v4u a = *(const v4u*)(X + (size_t)s * F + t * 4);
#pragma unroll
      for (int k = 0; k < 4; ++k) acc[k] += bfh(a[k]);
    } else {
      v2u a = *(const v2u*)(X + (size_t)s * F + t * 2);
#pragma unroll
      for (int k = 0; k < 2; ++k) acc[k] += bfh(a[k]);
    }
  }

  if (VEC == 4) {
    v4u o;
#pragma unroll
    for (int k = 0; k < 4; ++k) {
      float v = acc[k] * sc;
      if (bias) { v += bias[t * 4 + k]; if (do_relu) v = fmaxf(v, 0.f); }
      o[k] = rne16(v);
    }
    *(v4u*)(OUT + (size_t)row * F + t * 4) = o;
  } else {
    v2u o;
#pragma unroll
    for (int k = 0; k < 2; ++k) {
      float v = acc[k] * sc;
      if (bias) { v += bias[t * 2 + k]; if (do_relu) v = fmaxf(v, 0.f); }
      o[k] = rne16(v);
    }
    *(v2u*)(OUT + (size_t)row * F + t * 2) = o;
  }
}

template <int F>
__global__ void aggb_kernel(const int* __restrict__ off, const uint16_t* __restrict__ idx,
                            const float* __restrict__ scale,
                            const uint16_t* __restrict__ X,
                            uint16_t* __restrict__ OUT,
                            const float* __restrict__ bias, int do_relu) {
  agg_row<F>(off, idx, scale, X, OUT, blockIdx.x, bias, do_relu);
}

template <int F>
__global__ void agg2b_kernel(const int* __restrict__ off1, const uint16_t* __restrict__ idx1,
                             const float* __restrict__ sc1, uint16_t* __restrict__ OUT1, int n1,
                             const int* __restrict__ off2, const uint16_t* __restrict__ idx2,
                             const float* __restrict__ sc2, uint16_t* __restrict__ OUT2,
                             const uint16_t* __restrict__ X) {
  int row = blockIdx.x;
  if (row < n1) agg_row<F>(off1, idx1, sc1, X, OUT1, row, nullptr, 0);
  else          agg_row<F>(off2, idx2, sc2, X, OUT2, row - n1, nullptr, 0);
}

// Hyper tail: XCATB[:,40:80] = bf16(dinv*agg(EF40) + bias); zeros pad 80:96.
__global__ void agg40b_kernel(const int* __restrict__ off, const uint16_t* __restrict__ idx,
                              const float* __restrict__ scale,
                              const uint16_t* __restrict__ EF40,
                              const float* __restrict__ bias,
                              uint16_t* __restrict__ XCATB) {
  int row = blockIdx.x;
  int t = threadIdx.x;
  if (t < 8) {
    v2u z = {0, 0};
    *(v2u*)(XCATB + (size_t)row * 96 + 80 + t * 2) = z;
  }
  if (t >= 20) return;
  int j0 = off[row], j1 = off[row + 1];
  float sc = scale[row];
  float a0 = 0.f, a1 = 0.f;
  for (int j = j0; j < j1; ++j) {
    int s = idx[j];
    v2u v = *(const v2u*)(EF40 + (size_t)s * 40 + t * 2);
    a0 += bfh(v[0]);
    a1 += bfh(v[1]);
  }
  v2u o;
  o[0] = rne16(a0 * sc + bias[t * 2]);
  o[1] = rne16(a1 * sc + bias[t * 2 + 1]);
  *(v2u*)(XCATB + (size_t)row * 96 + 40 + t * 2) = o;
}

// SAGE tail: XCATB[:, :40] = bf16(deg_inv*agg(T40a) + T40b)
__global__ void agg40s_kernel(const int* __restrict__ off, const uint16_t* __restrict__ idx,
                              const float* __restrict__ scale,
                              const uint16_t* __restrict__ T40a,
                              const uint16_t* __restrict__ T40b,
                              uint16_t* __restrict__ XCATB) {
  int row = blockIdx.x;
  int t = threadIdx.x;
  if (t >= 20) return;
  int j0 = off[row], j1 = off[row + 1];
  float sc = scale[row];
  float a0 = 0.f, a1 = 0.f;
  for (int j = j0; j < j1; ++j) {
    int s = idx[j];
    v2u v = *(const v2u*)(T40a + (size_t)s * 40 + t * 2);
    a0 += bfh(v[0]);
    a1 += bfh(v[1]);
  }
  v2u b = *(const v2u*)(T40b + (size_t)row * 40 + t * 2);
  v2u o;
  o[0] = rne16(a0 * sc + bfh(b[0]));
  o[1] = rne16(a1 * sc + bfh(b[1]));
  *(v2u*)(XCATB + (size_t)row * 96 + t * 2) = o;
}

// ------------------------------------- bf16-A, split-W MFMA GEMM
// A/B frag: row|col = lane&15, k = (lane>>4)*8+j.  C/D: col = lane&15,
// row = (lane>>4)*4 + reg  (verified gfx950 mappings).
//
// F=256 path (m97-style): W staged via global_load_lds (16B, no VGPR round
// trip) from the chunk-major XOR-swizzled layout prep produced; ds_read
// applies the same XOR -> 2-way bank aliasing (free). A is preloaded into
// registers once per K-half, so the per-chunk barrier drain only waits on
// the W staging. Wave = 16 rows x 256 cols; works with 256-thr (4-wave)
// blocks for big N and 64-thr (1-wave) blocks for N=5000 CU coverage.
template <int K, int NF>
__device__ __forceinline__ void f256_half(const uint16_t* __restrict__ X,
                                          const uint16_t* __restrict__ Wh,
                                          const uint16_t* __restrict__ Wl,
                                          short* sW0, short* sW1,
                                          int rowA, int wave, int wpb,
                                          int lane, int q, int colsw,
                                          bool firstHalf, v4f* acc) {
  constexpr int NC = K / 32;
  v8s aR[NC];
#pragma unroll
  for (int kk = 0; kk < NC; ++kk)
    aR[kk] = *reinterpret_cast<const v8s*>(X + (size_t)rowA * K + kk * 32 + q * 8);
  int r = lane & 15;
  for (int c = 0; c < NC; ++c) {
    if (!(firstHalf && c == 0)) __syncthreads();   // readers of prev chunk done
    const uint16_t* bh = Wh + (size_t)c * 8192 + lane * 8;
    const uint16_t* bl = Wl + (size_t)c * 8192 + lane * 8;
    for (int p = wave; p < 16; p += wpb) {
      __builtin_amdgcn_global_load_lds((AS1CV)(bh + p * 512), (AS3V)(sW0 + p * 512), 16, 0, 0);
      __builtin_amdgcn_global_load_lds((AS1CV)(bl + p * 512), (AS3V)(sW1 + p * 512), 16, 0, 0);
    }
    __syncthreads();                               // drain -> LDS ready
#pragma unroll
    for (int ft = 0; ft < NF; ++ft) {
      const short* ph = sW0 + (ft * 16 + r) * 32 + colsw;
      const short* pl = sW1 + (ft * 16 + r) * 32 + colsw;
      v8s bhf = *reinterpret_cast<const v8s*>(ph);
      v8s blf = *reinterpret_cast<const v8s*>(pl);
      acc[ft] = __builtin_amdgcn_mfma_f32_16x16x32_bf16(aR[c], bhf, acc[ft], 0, 0, 0);
      acc[ft] = __builtin_amdgcn_mfma_f32_16x16x32_bf16(aR[c], blf, acc[ft], 0, 0, 0);
    }
  }
}

template <int K1, int K2, int F, bool OUTBF>
__global__ __launch_bounds__(256, 3) void lin2b_kernel(
    const uint16_t* __restrict__ X1, const uint16_t* __restrict__ W1h, const uint16_t* __restrict__ W1l,
    const uint16_t* __restrict__ X2, const uint16_t* __restrict__ W2h, const uint16_t* __restrict__ W2l,
    const float* __restrict__ bias, const uint16_t* __restrict__ addin,
    void* __restrict__ OUTP, int out_ld, int N, int do_relu) {
  constexpr int FP  = (F + 15) & ~15;
  constexpr int NF  = FP / 16;

  int tid  = threadIdx.x;
  int wave = tid >> 6, lane = tid & 63;
  int r = lane & 15, q = lane >> 4;

  if constexpr (F == 256) {
    __shared__ short sW[2][256][32];               // 32 KB, swizzled layout
    int wpb = blockDim.x >> 6;
    int row0 = blockIdx.x * (wpb << 4) + (wave << 4);
    int rowA = row0 + r; if (rowA > N - 1) rowA = N - 1;
    int colsw = (q ^ (r & 3)) << 3;                // swizzled k-subcol (shorts)

    v4f acc[NF];
#pragma unroll
    for (int i = 0; i < NF; ++i) acc[i] = (v4f){0.f, 0.f, 0.f, 0.f};

    f256_half<K1, NF>(X1, W1h, W1l, &sW[0][0][0], &sW[1][0][0],
                      rowA, wave, wpb, lane, q, colsw, true, acc);
    if constexpr (K2 > 0)
      f256_half<K2, NF>(X2, W2h, W2l, &sW[0][0][0], &sW[1][0][0],
                        rowA, wave, wpb, lane, q, colsw, false, acc);

#pragma unroll
    for (int ft = 0; ft < NF; ++ft) {
      int col = ft * 16 + r;
      float bv = bias ? bias[col] : 0.f;
#pragma unroll
      for (int i = 0; i < 4; ++i) {
        int row = row0 + q * 4 + i;
        if (row < N) {
          float v = acc[ft][i] + bv;
          if (addin) v += bfh(addin[(size_t)row * F + col]);
          if (do_relu) v = fmaxf(v, 0.f);
          size_t o = (size_t)row * out_ld + col;
          if (OUTBF) ((uint16_t*)OUTP)[o] = rne16(v);
          else ((float*)OUTP)[o] = v;
        }
      }
    }
  } else {
    // ---- original LDS row-strip schedule (F=40: row-major W)
    constexpr int NC1 = K1 / 32;
    constexpr int NCH = (K1 + (K2 > 0 ? K2 : 0)) / 32;
    constexpr int RS  = 40;
    __shared__ short sW[2][FP][RS];
    int srow = tid >> 2;
    int sj   = tid & 3;
    int row0 = blockIdx.x * 64 + wave * 16;
    int rowA = row0 + r; if (rowA > N - 1) rowA = N - 1;

    v4f acc[NF];
#pragma unroll
    for (int i = 0; i < NF; ++i) acc[i] = (v4f){0.f, 0.f, 0.f, 0.f};

    for (int c = 0; c < NCH; ++c) {
      const bool first = (K2 == 0) || (c < NC1);
      const uint16_t* Wh = first ? W1h : W2h;
      const uint16_t* Wl = first ? W1l : W2l;
      const uint16_t* Xs = first ? X1 : X2;
      const int K  = first ? K1 : K2;
      const int kc = (first ? c : c - NC1) * 32;

      if (c) __syncthreads();
      const v8s zz = {0, 0, 0, 0, 0, 0, 0, 0};
#pragma unroll
      for (int pass = 0; pass < (FP + 63) / 64; ++pass) {
        int row = srow + pass * 64;
        if (row < FP) {
          v8s hv = zz, lv = zz;
          if (row < F) {
            hv = *reinterpret_cast<const v8s*>(Wh + (size_t)row * K + kc + sj * 8);
            lv = *reinterpret_cast<const v8s*>(Wl + (size_t)row * K + kc + sj * 8);
          }
          *reinterpret_cast<v8s*>(&sW[0][row][sj * 8]) = hv;
          *reinterpret_cast<v8s*>(&sW[1][row][sj * 8]) = lv;
        }
      }
      v8s ah = *reinterpret_cast<const v8s*>(Xs + (size_t)rowA * K + kc + q * 8);
      __syncthreads();
#pragma unroll
      for (int ft = 0; ft < NF; ++ft) {
        v8s bh = *reinterpret_cast<const v8s*>(&sW[0][ft * 16 + r][q * 8]);
        v8s bl = *reinterpret_cast<const v8s*>(&sW[1][ft * 16 + r][q * 8]);
        acc[ft] = __builtin_amdgcn_mfma_f32_16x16x32_bf16(ah, bh, acc[ft], 0, 0, 0);
        acc[ft] = __builtin_amdgcn_mfma_f32_16x16x32_bf16(ah, bl, acc[ft], 0, 0, 0);
      }
    }

#pragma unroll
    for (int ft = 0; ft < NF; ++ft) {
      int col = ft * 16 + r;
      if (col < F) {
        float bv = bias ? bias[col] : 0.f;
#pragma unroll
        for (int i = 0; i < 4; ++i) {
          int row = row0 + q * 4 + i;
          if (row < N) {
            float v = acc[ft][i] + bv;
            if (addin) v += bfh(addin[(size_t)row * F + col]);
            if (do_relu) v = fmaxf(v, 0.f);
            size_t o = (size_t)row * out_ld + col;
            if (OUTBF) ((uint16_t*)OUTP)[o] = rne16(v);
            else ((float*)OUTP)[o] = v;
          }
        }
      }
    }
  }
}

// Dual-output 40-col GEMM (K=256): OUT1 = X*W1^T, OUT2 = X*W2^T + b2.
__global__ __launch_bounds__(256, 4) void lin40ab_kernel(
    const uint16_t* __restrict__ X,
    const uint16_t* __restrict__ W1h, const uint16_t* __restrict__ W1l,
    const uint16_t* __restrict__ W2h, const uint16_t* __restrict__ W2l,
    const float* __restrict__ bias2,
    uint16_t* __restrict__ OUT1, uint16_t* __restrict__ OUT2, int N) {
  constexpr int K = 256, F = 40, FP = 48, NF = 3, RS = 40;
  __shared__ short sW[2][2][FP][RS];

  int tid  = threadIdx.x;
  int wave = tid >> 6, lane = tid & 63;
  int r = lane & 15, q = lane >> 4;
  int row0 = blockIdx.x * 64 + wave * 16;
  int rowA = row0 + r; if (rowA > N - 1) rowA = N - 1;
  int srow = tid >> 2, sj = tid & 3;

  v4f acc[2][NF];
#pragma unroll
  for (int w = 0; w < 2; ++w)
#pragma unroll
    for (int i = 0; i < NF; ++i) acc[w][i] = (v4f){0.f, 0.f, 0.f, 0.f};

  for (int c = 0; c < K / 32; ++c) {
    int kc = c * 32;
    if (c) __syncthreads();
    if (srow < FP) {
      const v8s zz = {0, 0, 0, 0, 0, 0, 0, 0};
      v8s a = zz, b = zz, cc = zz, d = zz;
      if (srow < F) {
        a  = *reinterpret_cast<const v8s*>(W1h + (size_t)srow * K + kc + sj * 8);
        b  = *reinterpret_cast<const v8s*>(W1l + (size_t)srow * K + kc + sj * 8);
        cc = *reinterpret_cast<const v8s*>(W2h + (size_t)srow * K + kc + sj * 8);
        d  = *reinterpret_cast<const v8s*>(W2l + (size_t)srow * K + kc + sj * 8);
      }
      *reinterpret_cast<v8s*>(&sW[0][0][srow][sj * 8]) = a;
      *reinterpret_cast<v8s*>(&sW[0][1][srow][sj * 8]) = b;
      *reinterpret_cast<v8s*>(&sW[1][0][srow][sj * 8]) = cc;
      *reinterpret_cast<v8s*>(&sW[1][1][srow][sj * 8]) = d;
    }
    v8s ah = *reinterpret_cast<const v8s*>(X + (size_t)rowA * K + kc + q * 8);
    __syncthreads();
#pragma unroll
    for (int w = 0; w < 2; ++w)
#pragma unroll
      for (int ft = 0; ft < NF; ++ft) {
        v8s bh = *reinterpret_cast<const v8s*>(&sW[w][0][ft * 16 + r][q * 8]);
        v8s bl = *reinterpret_cast<const v8s*>(&sW[w][1][ft * 16 + r][q * 8]);
        acc[w][ft] = __builtin_amdgcn_mfma_f32_16x16x32_bf16(ah, bh, acc[w][ft], 0, 0, 0);
        acc[w][ft] = __builtin_amdgcn_mfma_f32_16x16x32_bf16(ah, bl, acc[w][ft], 0, 0, 0);
      }
  }

#pragma unroll
  for (int ft = 0; ft < NF; ++ft) {
    int col = ft * 16 + r;
    if (col < F) {
      float bv = bias2[col];
#pragma unroll
      for (int i = 0; i < 4; ++i) {
        int row = row0 + q * 4 + i;
        if (row < N) {
          OUT1[(size_t)row * F + col] = rne16(acc[0][ft][i]);
          OUT2[(size_t)row * F + col] = rne16(acc[1][ft][i] + bv);
        }
      }
    }
  }
}

// ---------------- final: MFMA GEMM (K=96, F=40) + fused log-softmax
__global__ __launch_bounds__(256, 4) void final_mfma_kernel(
    const uint16_t* __restrict__ XB96,
    const uint16_t* __restrict__ Wh, const uint16_t* __restrict__ Wl,
    const float* __restrict__ lpb, float* __restrict__ out, int N) {
  constexpr int K = 96, F = 40, FP = 48, NF = 3, RS = 40;
  __shared__ short sW[2][FP][RS];

  int tid  = threadIdx.x;
  int wave = tid >> 6, lane = tid & 63;
  int r = lane & 15, q = lane >> 4;
  int row0 = blockIdx.x * 64 + wave * 16;
  int rowA = row0 + r; if (rowA > N - 1) rowA = N - 1;
  int srow = tid >> 2, sj = tid & 3;

  v4f acc[NF];
#pragma unroll
  for (int i = 0; i < NF; ++i) acc[i] = (v4f){0.f, 0.f, 0.f, 0.f};

  for (int c = 0; c < 3; ++c) {
    int kc = c * 32;
    if (c) __syncthreads();
    if (srow < FP) {
      const v8s zz = {0, 0, 0, 0, 0, 0, 0, 0};
      v8s hv = zz, lv = zz;
      if (srow < F) {
        hv = *reinterpret_cast<const v8s*>(Wh + (size_t)srow * K + kc + sj * 8);
        lv = *reinterpret_cast<const v8s*>(Wl + (size_t)srow * K + kc + sj * 8);
      }
      *reinterpret_cast<v8s*>(&sW[0][srow][sj * 8]) = hv;
      *reinterpret_cast<v8s*>(&sW[1][srow][sj * 8]) = lv;
    }
    v8s ah = *reinterpret_cast<const v8s*>(XB96 + (size_t)rowA * K + kc + q * 8);
    __syncthreads();
#pragma unroll
    for (int ft = 0; ft < NF; ++ft) {
      v8s bh = *reinterpret_cast<const v8s*>(&sW[0][ft * 16 + r][q * 8]);
      v8s bl = *reinterpret_cast<const v8s*>(&sW[1][ft * 16 + r][q * 8]);
      acc[ft] = __builtin_amdgcn_mfma_f32_16x16x32_bf16(ah, bh, acc[ft], 0, 0, 0);
      acc[ft] = __builtin_amdgcn_mfma_f32_16x16x32_bf16(ah, bl, acc[ft], 0, 0, 0);
    }
  }

  float b0 = lpb[r], b1 = lpb[16 + r];
  float b2 = (r < 8) ? lpb[32 + r] : 0.f;
#pragma unroll
  for (int i = 0; i < 4; ++i) {
    int row = row0 + q * 4 + i;
    float l0 = acc[0][i] + b0;
    float l1 = acc[1][i] + b1;
    float l2 = (r < 8) ? (acc[2][i] + b2) : -1e30f;
    float m = fmaxf(fmaxf(l0, l1), l2);
#pragma unroll
    for (int d = 1; d < 16; d <<= 1) m = fmaxf(m, __shfl_xor(m, d));
    float e = __expf(l0 - m) + __expf(l1 - m) + ((r < 8) ? __expf(l2 - m) : 0.f);
#pragma unroll
    for (int d = 1; d < 16; d <<= 1) e += __shfl_xor(e, d);
    if (row < N) {
      float ls = m + __logf(e);
      out[(size_t)row * 40 + r]      = l0 - ls;
      out[(size_t)row * 40 + 16 + r] = l1 - ls;
      if (r < 8) out[(size_t)row * 40 + 32 + r] = l2 - ls;
    }
  }
}

// ---------------------------------------------------------------- launcher
extern "C" void kernel_launch(void* const* d_in, const int* in_sizes, int n_in,
                              void* d_out, int out_size, void* d_ws, size_t ws_size,
                              hipStream_t stream) {
  const float* x      = (const float*)d_in[0];
  const int* src      = (const int*)d_in[1];
  const int* dst      = (const int*)d_in[2];
  const int* he_node  = (const int*)d_in[3];
  const int* he_edge  = (const int*)d_in[4];
  const float* s0wl = (const float*)d_in[5],  *s0wr = (const float*)d_in[6],  *s0b = (const float*)d_in[7];
  const float* s1wl = (const float*)d_in[8],  *s1wr = (const float*)d_in[9],  *s1b = (const float*)d_in[10];
  const float* s2wl = (const float*)d_in[11], *s2wr = (const float*)d_in[12], *s2b = (const float*)d_in[13];
  const float* h0w = (const float*)d_in[14], *h0b = (const float*)d_in[15];
  const float* h1w = (const float*)d_in[16], *h1b = (const float*)d_in[17];
  const float* h2w = (const float*)d_in[18], *h2b = (const float*)d_in[19];
  const float* h3w = (const float*)d_in[20], *h3b = (const float*)d_in[21];
  const float* h4w = (const float*)d_in[22], *h4b = (const float*)d_in[23];
  const float* lpw = (const float*)d_in[24], *lpb = (const float*)d_in[25];
  float* out = (float*)d_out;

  char* p = (char*)d_ws;
  auto carve = [&](size_t bytes) -> char* {
    char* r = p;
    p += (bytes + 255) & ~(size_t)255;
    return r;
  };
  int* adj_off  = (int*)carve((size_t)(N_NODES + 1) * 4);
  uint16_t* adj_src  = (uint16_t*)carve((size_t)N_EDGE * 2);
  int* heg_off  = (int*)carve((size_t)(N_HE + 1) * 4);
  uint16_t* heg_node = (uint16_t*)carve((size_t)N_INC * 2);
  int* hng_off  = (int*)carve((size_t)(N_NODES + 1) * 4);
  uint16_t* hng_edge = (uint16_t*)carve((size_t)N_INC * 2);
  int* gcnt     = (int*)carve((size_t)NBREL * 4);
  int* brel     = (int*)carve((size_t)NBREL * 4);
  int* gbb      = (int*)carve((size_t)278 * 4);
  uint32_t* stg_adj = (uint32_t*)carve((size_t)N_EDGE * 4);
  uint32_t* stg_heg = (uint32_t*)carve((size_t)N_INC * 4);
  uint32_t* stg_hng = (uint32_t*)carve((size_t)N_INC * 4);
  float* deg_inv = (float*)carve((size_t)N_NODES * 4);
  float* binv    = (float*)carve((size_t)N_HE * 4);
  float* dinv    = (float*)carve((size_t)N_NODES * 4);
  uint16_t* Wh = (uint16_t*)carve((size_t)W_TOTAL * 2);
  uint16_t* Wl = (uint16_t*)carve((size_t)W_TOTAL * 2);
  uint16_t* lpWh = (uint16_t*)carve((size_t)40 * 96 * 2);
  uint16_t* lpWl = (uint16_t*)carve((size_t)40 * 96 * 2);
  uint16_t* XB = (uint16_t*)carve((size_t)N_NODES * 128 * 2);
  uint16_t* U  = (uint16_t*)carve((size_t)N_NODES * 128 * 2);
  uint16_t* NA = (uint16_t*)carve((size_t)N_NODES * 256 * 2);
  uint16_t* NB_ = (uint16_t*)carve((size_t)N_NODES * 256 * 2);
  uint16_t* NC = (uint16_t*)carve((size_t)N_NODES * 256 * 2);
  uint16_t* EFa = (uint16_t*)carve((size_t)N_HE * 256 * 2);
  uint16_t* EFb = (uint16_t*)carve((size_t)N_HE * 256 * 2);
  uint16_t* T40 = (uint16_t*)carve((size_t)N_NODES * 40 * 2);
  uint16_t* T40B = (uint16_t*)carve((size_t)N_NODES * 40 * 2);
  uint16_t* T40H = (uint16_t*)carve((size_t)N_NODES * 40 * 2);
  uint16_t* XCATB = (uint16_t*)carve((size_t)N_NODES * 96 * 2);

  const int GL = (N_NODES + 63) / 64;     // 782 blocks x 256 thr (4-wave)
  const int GSW = (N_HE + 15) / 16;       // 313 blocks x 64 thr (1-wave)

  // ---- prep (zero + weight split + lpw split + x cvt) and binned CSR build
  prep_kernel<<<8052, 256, 0, stream>>>(gcnt, brel,
                                        s0wl, s0wr, s1wl, s1wr, s2wl, s2wr,
                                        h0w, h1w, h2w, h3w, h4w, Wh, Wl,
                                        lpw, lpWh, lpWl, x, XB);
  bhist_kernel<<<392, 256, 0, stream>>>(dst, he_edge, he_node, gcnt);
  bscan_kernel<<<1, 256, 0, stream>>>(gcnt, gbb, adj_off, heg_off, hng_off);
  binA_kernel<<<392, 256, 0, stream>>>(src, dst, he_node, he_edge,
                                       gbb, brel, stg_adj, stg_heg, stg_hng);
  binB2_kernel<<<275, 256, 0, stream>>>(gbb, stg_adj, stg_heg, stg_hng,
                                        adj_off, heg_off, hng_off,
                                        deg_inv, binv, dinv,
                                        adj_src, heg_node, hng_edge);

  // ---- merged layer-0 gathers (SAGE node-agg + hyper he-agg, both from XB)
  agg2b_kernel<128><<<N_NODES + N_HE, 64, 0, stream>>>(
      adj_off, adj_src, deg_inv, U, N_NODES,
      heg_off, heg_node, binv, EFa, XB);

  // ---- SAGE branch
  lin2b_kernel<128, 128, 256, true><<<GL, 256, 0, stream>>>(
      U, Wh + 0, Wl + 0, XB, Wh + 32768, Wl + 32768, s0b, nullptr, NA, 256, N_NODES, 1);
  aggb_kernel<256><<<N_NODES, 64, 0, stream>>>(adj_off, adj_src, deg_inv, NA, NB_, nullptr, 0);
  lin2b_kernel<256, 256, 256, true><<<GL, 256, 0, stream>>>(
      NB_, Wh + 65536, Wl + 65536, NA, Wh + 131072, Wl + 131072, s1b, nullptr, NC, 256, N_NODES, 1);
  lin40ab_kernel<<<GL, 256, 0, stream>>>(
      NC, Wh + 196608, Wl + 196608, Wh + 206848, Wl + 206848, s2b, T40, T40B, N_NODES);
  agg40s_kernel<<<N_NODES, 64, 0, stream>>>(adj_off, adj_src, deg_inv, T40, T40B, XCATB);

  // ---- Hypergraph branch: heagg -> tiny GEMM (5000 rows) -> nodeagg+bias+relu
  lin2b_kernel<128, 0, 256, true><<<GSW, 64, 0, stream>>>(
      EFa, Wh + 217088, Wl + 217088, nullptr, nullptr, nullptr, nullptr, nullptr, EFb, 256, N_HE, 0);
  aggb_kernel<256><<<N_NODES, 64, 0, stream>>>(hng_off, hng_edge, dinv, EFb, NC, h0b, 1);

  aggb_kernel<256><<<N_HE, 64, 0, stream>>>(heg_off, heg_node, binv, NC, EFa, nullptr, 0);
  lin2b_kernel<256, 0, 256, true><<<GSW, 64, 0, stream>>>(
      EFa, Wh + 249856, Wl + 249856, nullptr, nullptr, nullptr, nullptr, nullptr, EFb, 256, N_HE, 0);
  aggb_kernel<256><<<N_NODES, 64, 0, stream>>>(hng_off, hng_edge, dinv, EFb, NC, h1b, 1);

  aggb_kernel<256><<<N_HE, 64, 0, stream>>>(heg_off, heg_node, binv, NC, EFa, nullptr, 0);
  lin2b_kernel<256, 0, 256, true><<<GSW, 64, 0, stream>>>(
      EFa, Wh + 315392, Wl + 315392, nullptr, nullptr, nullptr, nullptr, nullptr, EFb, 256, N_HE, 0);
  aggb_kernel<256><<<N_NODES, 64, 0, stream>>>(hng_off, hng_edge, dinv, EFb, NC, h2b, 1);

  aggb_kernel<256><<<N_HE, 64, 0, stream>>>(heg_off, heg_node, binv, NC, EFa, nullptr, 0);
  lin2b_kernel<256, 0, 256, true><<<GSW, 64, 0, stream>>>(
      EFa, Wh + 380928, Wl + 380928, nullptr, nullptr, nullptr, nullptr, nullptr, EFb, 256, N_HE, 0);
  aggb_kernel<256><<<N_NODES, 64, 0, stream>>>(hng_off, hng_edge, dinv, EFb, NC, h3b, 1);

  // layer 4 (F=40): transform node features first, then two aggs
  lin2b_kernel<256, 0, 40, true><<<GL, 256, 0, stream>>>(
      NC, Wh + 446464, Wl + 446464, nullptr, nullptr, nullptr, nullptr, nullptr, T40H, 40, N_NODES, 0);
  aggb_kernel<40><<<N_HE, 64, 0, stream>>>(heg_off, heg_node, binv, T40H, EFa, nullptr, 0);
  agg40b_kernel<<<N_NODES, 64, 0, stream>>>(hng_off, hng_edge, dinv, EFa, h4b, XCATB);

  // ---- final MFMA linear + fused log_softmax
  final_mfma_kernel<<<GL, 256, 0, stream>>>(XCATB, lpWh, lpWl, lpb, out, N_NODES);
}

// Round 5
// 801.342 us; speedup vs baseline: 1.3154x; 1.3154x over previous
//
#include <hip/hip_runtime.h>
#include <hip/hip_bf16.h>
#include <cstdint>
#include <cstddef>

typedef __hip_bfloat16 bf16;
typedef short v8s __attribute__((ext_vector_type(8)));
typedef float v4f __attribute__((ext_vector_type(4)));
typedef unsigned short v8u __attribute__((ext_vector_type(8)));
typedef unsigned short v4u __attribute__((ext_vector_type(4)));
typedef unsigned short v2u __attribute__((ext_vector_type(2)));

#define N_NODES 50000
#define N_HE    5000
#define N_EDGE  800000
#define N_INC   400000
#define W_TOTAL 456704
#define NBREL   275   // 98 adj + 79 heg + 98 hng bucket cursors

#define AS1CV const __attribute__((address_space(1))) void*
#define AS3V  __attribute__((address_space(3))) void*

__device__ inline float bfh(uint32_t u) { return __uint_as_float(u << 16); }
__device__ inline uint16_t rne16(float f) {
  uint32_t u = __float_as_uint(f);
  return (uint16_t)((u + 0x7FFFu + ((u >> 16) & 1u)) >> 16);
}

// ---- prep: zero gcnt+brel + split weights (incl lpw, stride 96) + cvt x
// F=256 weight matrices are stored CHUNK-MAJOR + XOR-swizzled so that
// global_load_lds linear writes produce a bank-friendly LDS layout:
//   element w[row][c*32 + q*8 + e] -> idx c*8192 + row*32 + ((q^(row&3))<<3) + e
// F=40 matrices (s2wl/s2wr/h4w) stay row-major (old LDS path).
__global__ void prep_kernel(int* gcnt, int* brel,
                            const float* s0wl, const float* s0wr,
                            const float* s1wl, const float* s1wr,
                            const float* s2wl, const float* s2wr,
                            const float* h0w, const float* h1w,
                            const float* h2w, const float* h3w, const float* h4w,
                            uint16_t* hi, uint16_t* lo,
                            const float* lpw, uint16_t* lpWh, uint16_t* lpWl,
                            const float* X, uint16_t* XB) {
  int b = blockIdx.x;
  if (b < 3) {
    int i = b * 256 + threadIdx.x;
    if (i < NBREL) gcnt[i] = 0;
    else if (i < 2 * NBREL) brel[i - NBREL] = 0;
    return;
  }
  if (b < 1787) {
    int i = (b - 3) * 256 + threadIdx.x;
    if (i >= W_TOTAL) return;
    const float* src; int base; int kln2; int sw;
    if (i < 32768)       { src = s0wl; base = 0;      kln2 = 7; sw = 1; }
    else if (i < 65536)  { src = s0wr; base = 32768;  kln2 = 7; sw = 1; }
    else if (i < 131072) { src = s1wl; base = 65536;  kln2 = 8; sw = 1; }
    else if (i < 196608) { src = s1wr; base = 131072; kln2 = 8; sw = 1; }
    else if (i < 206848) { src = s2wl; base = 196608; kln2 = 8; sw = 0; }
    else if (i < 217088) { src = s2wr; base = 206848; kln2 = 8; sw = 0; }
    else if (i < 249856) { src = h0w;  base = 217088; kln2 = 7; sw = 1; }
    else if (i < 315392) { src = h1w;  base = 249856; kln2 = 8; sw = 1; }
    else if (i < 380928) { src = h2w;  base = 315392; kln2 = 8; sw = 1; }
    else if (i < 446464) { src = h3w;  base = 380928; kln2 = 8; sw = 1; }
    else                 { src = h4w;  base = 446464; kln2 = 8; sw = 0; }
    int j = i - base;
    float v = src[j];
    int nj = j;
    if (sw) {
      int row = j >> kln2;
      int col = j & ((1 << kln2) - 1);
      int c = col >> 5, qq = (col >> 3) & 3, e = col & 7;
      nj = c * 8192 + row * 32 + ((qq ^ (row & 3)) << 3) + e;
    }
    uint16_t hb = rne16(v);
    hi[base + nj] = hb;
    lo[base + nj] = rne16(v - bfh(hb));
    return;
  }
  if (b < 1802) {
    int i = (b - 1787) * 256 + threadIdx.x;   // 40 rows x 96 cols
    if (i >= 40 * 96) return;
    int row = i / 96, col = i - row * 96;
    float v = (col < 80) ? lpw[row * 80 + col] : 0.f;
    uint16_t hb = rne16(v);
    lpWh[i] = hb;
    lpWl[i] = rne16(v - bfh(hb));
    return;
  }
  {
    int i = (b - 1802) * 256 + threadIdx.x;   // v4 index
    if (i >= N_NODES * 32) return;
    v4f v = *((const v4f*)X + i);
    v4u o;
    o[0] = rne16(v[0]); o[1] = rne16(v[1]); o[2] = rne16(v[2]); o[3] = rne16(v[3]);
    *((v4u*)XB + i) = o;
  }
}

// ---------------- bucket-level histogram (LDS-local; replaces hist_kernel)
template <int NB, int SH>
__device__ inline void bhist_section(const int* __restrict__ key_arr, int n, int blk,
                                     int* __restrict__ gcnt) {
  __shared__ int h[128];
  int t = threadIdx.x;
  for (int k = t; k < NB; k += 256) h[k] = 0;
  __syncthreads();
  int e0 = blk * 4096;
  int cnt = min(4096, n - e0);
  for (int k = t; k < cnt; k += 256) atomicAdd(&h[key_arr[e0 + k] >> SH], 1);
  __syncthreads();
  for (int k = t; k < NB; k += 256) atomicAdd(&gcnt[k], h[k]);
}

__global__ __launch_bounds__(256) void bhist_kernel(
    const int* __restrict__ dst, const int* __restrict__ he_edge,
    const int* __restrict__ he_node, int* gcnt) {
  int b = blockIdx.x;
  if (b < 196)      bhist_section<98, 9>(dst, N_EDGE, b, gcnt);
  else if (b < 294) bhist_section<79, 6>(he_edge, N_INC, b - 196, gcnt + 98);
  else              bhist_section<98, 9>(he_node, N_INC, b - 294, gcnt + 177);
}

// ---------------- bucket-base scan (one wave per section) + CSR sentinels
__global__ void bscan_kernel(const int* __restrict__ gcnt, int* gbb,
                             int* adj_off, int* heg_off, int* hng_off) {
  int t = threadIdx.x;
  if (t == 0)        { int s = 0; for (int b = 0; b < 98; ++b) { gbb[b] = s; s += gcnt[b]; } gbb[98] = s; }
  else if (t == 64)  { int s = 0; for (int b = 0; b < 79; ++b) { gbb[99 + b] = s; s += gcnt[98 + b]; } gbb[99 + 79] = s; }
  else if (t == 128) { int s = 0; for (int b = 0; b < 98; ++b) { gbb[179 + b] = s; s += gcnt[177 + b]; } gbb[179 + 98] = s; }
  else if (t == 192) { adj_off[N_NODES] = N_EDGE; heg_off[N_HE] = N_INC; hng_off[N_NODES] = N_INC; }
}

// ---------------- binned two-phase fill (no scatter write amplification)
template <int NB, int SH>
__device__ inline void binA_section(const int* __restrict__ key_arr,
                                    const int* __restrict__ pay_arr, int n, int blk,
                                    const int* __restrict__ bb,
                                    int* brel, uint32_t* __restrict__ stg) {
  __shared__ int lcnt[128], lscan[128], lcnt2[128], gbase[128];
  __shared__ uint32_t sstage[4096];
  int t = threadIdx.x;
  int e0 = blk * 4096;
  int cnt = min(4096, n - e0);
  for (int k = t; k < NB; k += 256) { lcnt[k] = 0; lcnt2[k] = 0; }
  __syncthreads();
  for (int k = t; k < cnt; k += 256) atomicAdd(&lcnt[key_arr[e0 + k] >> SH], 1);
  __syncthreads();
  if (t == 0) {
    int s = 0;
    for (int b = 0; b < NB; ++b) { lscan[b] = s; s += lcnt[b]; }
  }
  __syncthreads();
  if (t < NB) gbase[t] = bb[t] + atomicAdd(&brel[t], lcnt[t]);
  __syncthreads();
  for (int k = t; k < cnt; k += 256) {
    int key = key_arr[e0 + k];
    int pay = pay_arr[e0 + k];
    int b = key >> SH;
    int r = atomicAdd(&lcnt2[b], 1);
    sstage[lscan[b] + r] = ((uint32_t)pay << 16) | (uint32_t)key;
  }
  __syncthreads();
  for (int b = 0; b < NB; ++b) {
    int len = lcnt[b], ls = lscan[b], gb = gbase[b];
    for (int k = t; k < len; k += 256) stg[gb + k] = sstage[ls + k];
  }
}

__global__ __launch_bounds__(256) void binA_kernel(
    const int* __restrict__ src, const int* __restrict__ dst,
    const int* __restrict__ he_node, const int* __restrict__ he_edge,
    const int* __restrict__ gbb, int* brel,
    uint32_t* stg_adj, uint32_t* stg_heg, uint32_t* stg_hng) {
  int b = blockIdx.x;
  if (b < 196)      binA_section<98, 9>(dst, src, N_EDGE, b, gbb, brel, stg_adj);
  else if (b < 294) binA_section<79, 6>(he_edge, he_node, N_INC, b - 196, gbb + 99, brel + 98, stg_heg);
  else              binA_section<98, 9>(he_node, he_edge, N_INC, b - 294, gbb + 179, brel + 177, stg_hng);
}

// Pass B + per-node count/scan: writes CSR offsets, reciprocal scales, payloads.
template <int BS, int SH, int MODE>
__device__ inline void binB2_section(int bkt, const int* __restrict__ bb, int nkeys,
                                     const uint32_t* __restrict__ stg,
                                     int* __restrict__ off_out,
                                     float* __restrict__ scl,
                                     uint16_t* __restrict__ out) {
  __shared__ int lcnt[512], loff[512], lcur[512];
  __shared__ int ws[4];
  int t = threadIdx.x;
  int nb0 = bkt << SH;
  int nb1 = min(nb0 + BS, nkeys);
  int nn = nb1 - nb0;
  int e0 = bb[bkt], e1 = bb[bkt + 1];
  for (int k = t; k < nn; k += 256) lcnt[k] = 0;
  __syncthreads();
  for (int e = e0 + t; e < e1; e += 256)
    atomicAdd(&lcnt[(int)(stg[e] & 0xFFFFu) - nb0], 1);
  __syncthreads();
  // exclusive scan over nn counts (2 per thread, shfl within wave, 4 waves)
  int lane = t & 63, wv = t >> 6;
  int i0 = 2 * t;
  int a0 = (i0 < nn) ? lcnt[i0] : 0;
  int a1 = (i0 + 1 < nn) ? lcnt[i0 + 1] : 0;
  int ts = a0 + a1;
  int val = ts;
#pragma unroll
  for (int d = 1; d < 64; d <<= 1) {
    int x = __shfl_up(val, d);
    if (lane >= d) val += x;
  }
  if (lane == 63) ws[wv] = val;
  __syncthreads();
  if (t == 0) {
    int s = 0;
#pragma unroll
    for (int w = 0; w < 4; ++w) { int v = ws[w]; ws[w] = s; s += v; }
  }
  __syncthreads();
  int excl = ws[wv] + (val - ts);
  if (i0 < nn) loff[i0] = excl;
  if (i0 + 1 < nn) loff[i0 + 1] = excl + a0;
  __syncthreads();
  for (int k = t; k < nn; k += 256) {
    int base = e0 + loff[k];
    off_out[nb0 + k] = base;
    lcur[k] = base;
    int c = lcnt[k];
    scl[nb0 + k] = (MODE == 0) ? 1.0f / (float)(c > 1 ? c : 1)
                               : (c > 0 ? 1.0f / (float)c : 0.f);
  }
  __syncthreads();
  for (int e = e0 + t; e < e1; e += 256) {
    uint32_t v = stg[e];
    int key = (int)(v & 0xFFFFu);
    int p = atomicAdd(&lcur[key - nb0], 1);
    out[p] = (uint16_t)(v >> 16);
  }
}

__global__ __launch_bounds__(256) void binB2_kernel(
    const int* __restrict__ gbb,
    const uint32_t* __restrict__ stg_adj, const uint32_t* __restrict__ stg_heg,
    const uint32_t* __restrict__ stg_hng,
    int* adj_off, int* heg_off, int* hng_off,
    float* deg_inv, float* binv, float* dinv,
    uint16_t* adj_src, uint16_t* heg_node, uint16_t* hng_edge) {
  int b = blockIdx.x;
  if (b < 98)       binB2_section<512, 9, 0>(b, gbb, N_NODES, stg_adj, adj_off, deg_inv, adj_src);
  else if (b < 177) binB2_section<64, 6, 1>(b - 98, gbb + 99, N_HE, stg_heg, heg_off, binv, heg_node);
  else              binB2_section<512, 9, 1>(b - 177, gbb + 179, N_NODES, stg_hng, hng_off, dinv, hng_edge);
}

// ------------------------------- gather-mean row body (uint16 CSR idx)
template <int F>
__device__ inline void agg_row(const int* __restrict__ off, const uint16_t* __restrict__ idx,
                               const float* __restrict__ scale,
                               const uint16_t* __restrict__ X,
                               uint16_t* __restrict__ OUT, int row,
                               const float* __restrict__ bias, int do_relu) {
  constexpr int VEC = (F >= 256) ? 4 : 2;
  int t = threadIdx.x;
  if (t * VEC >= F) return;
  int j0 = off[row], j1 = off[row + 1];
  float sc = scale[row];
  float acc[VEC];
#pragma unroll
  for (int k = 0; k < VEC; ++k) acc[k] = 0.f;

  int j = j0;
  for (; j + 7 < j1; j += 8) {
    int s[8];
#pragma unroll
    for (int u = 0; u < 8; ++u) s[u] = idx[j + u];
    if (VEC == 4) {
      v4u v[8];
#pragma unroll
      for (int u = 0; u < 8; ++u) v[u] = *(const v4u*)(X + (size_t)s[u] * F + t * 4);
#pragma unroll
      for (int u = 0; u < 8; ++u)
#pragma unroll
        for (int k = 0; k < 4; ++k) acc[k] += bfh(v[u][k]);
    } else {
      v2u v[8];
#pragma unroll
      for (int u = 0; u < 8; ++u) v[u] = *(const v2u*)(X + (size_t)s[u] * F + t * 2);
#pragma unroll
      for (int u = 0; u < 8; ++u)
#pragma unroll
        for (int k = 0; k < 2; ++k) acc[k] += bfh(v[u][k]);
    }
  }
  for (; j < j1; ++j) {
    int s = idx[j];
    if (VEC == 4) {
      v4u a = *(const v4u*)(X + (size_t)s * F + t * 4);
#pragma unroll
      for (int k = 0; k < 4; ++k) acc[k] += bfh(a[k]);
    } else {
      v2u a = *(const v2u*)(X + (size_t)s * F + t * 2);
#pragma unroll
      for (int k = 0; k < 2; ++k) acc[k] += bfh(a[k]);
    }
  }

  if (VEC == 4) {
    v4u o;
#pragma unroll
    for (int k = 0; k < 4; ++k) {
      float v = acc[k] * sc;
      if (bias) { v += bias[t * 4 + k]; if (do_relu) v = fmaxf(v, 0.f); }
      o[k] = rne16(v);
    }
    *(v4u*)(OUT + (size_t)row * F + t * 4) = o;
  } else {
    v2u o;
#pragma unroll
    for (int k = 0; k < 2; ++k) {
      float v = acc[k] * sc;
      if (bias) { v += bias[t * 2 + k]; if (do_relu) v = fmaxf(v, 0.f); }
      o[k] = rne16(v);
    }
    *(v2u*)(OUT + (size_t)row * F + t * 2) = o;
  }
}

template <int F>
__global__ void aggb_kernel(const int* __restrict__ off, const uint16_t* __restrict__ idx,
                            const float* __restrict__ scale,
                            const uint16_t* __restrict__ X,
                            uint16_t* __restrict__ OUT,
                            const float* __restrict__ bias, int do_relu) {
  agg_row<F>(off, idx, scale, X, OUT, blockIdx.x, bias, do_relu);
}

template <int F>
__global__ void agg2b_kernel(const int* __restrict__ off1, const uint16_t* __restrict__ idx1,
                             const float* __restrict__ sc1, uint16_t* __restrict__ OUT1, int n1,
                             const int* __restrict__ off2, const uint16_t* __restrict__ idx2,
                             const float* __restrict__ sc2, uint16_t* __restrict__ OUT2,
                             const uint16_t* __restrict__ X) {
  int row = blockIdx.x;
  if (row < n1) agg_row<F>(off1, idx1, sc1, X, OUT1, row, nullptr, 0);
  else          agg_row<F>(off2, idx2, sc2, X, OUT2, row - n1, nullptr, 0);
}

// Hyper tail: XCATB[:,40:80] = bf16(dinv*agg(EF40) + bias); zeros pad 80:96.
__global__ void agg40b_kernel(const int* __restrict__ off, const uint16_t* __restrict__ idx,
                              const float* __restrict__ scale,
                              const uint16_t* __restrict__ EF40,
                              const float* __restrict__ bias,
                              uint16_t* __restrict__ XCATB) {
  int row = blockIdx.x;
  int t = threadIdx.x;
  if (t < 8) {
    v2u z = {0, 0};
    *(v2u*)(XCATB + (size_t)row * 96 + 80 + t * 2) = z;
  }
  if (t >= 20) return;
  int j0 = off[row], j1 = off[row + 1];
  float sc = scale[row];
  float a0 = 0.f, a1 = 0.f;
  for (int j = j0; j < j1; ++j) {
    int s = idx[j];
    v2u v = *(const v2u*)(EF40 + (size_t)s * 40 + t * 2);
    a0 += bfh(v[0]);
    a1 += bfh(v[1]);
  }
  v2u o;
  o[0] = rne16(a0 * sc + bias[t * 2]);
  o[1] = rne16(a1 * sc + bias[t * 2 + 1]);
  *(v2u*)(XCATB + (size_t)row * 96 + 40 + t * 2) = o;
}

// SAGE tail: XCATB[:, :40] = bf16(deg_inv*agg(T40a) + T40b)
__global__ void agg40s_kernel(const int* __restrict__ off, const uint16_t* __restrict__ idx,
                              const float* __restrict__ scale,
                              const uint16_t* __restrict__ T40a,
                              const uint16_t* __restrict__ T40b,
                              uint16_t* __restrict__ XCATB) {
  int row = blockIdx.x;
  int t = threadIdx.x;
  if (t >= 20) return;
  int j0 = off[row], j1 = off[row + 1];
  float sc = scale[row];
  float a0 = 0.f, a1 = 0.f;
  for (int j = j0; j < j1; ++j) {
    int s = idx[j];
    v2u v = *(const v2u*)(T40a + (size_t)s * 40 + t * 2);
    a0 += bfh(v[0]);
    a1 += bfh(v[1]);
  }
  v2u b = *(const v2u*)(T40b + (size_t)row * 40 + t * 2);
  v2u o;
  o[0] = rne16(a0 * sc + bfh(b[0]));
  o[1] = rne16(a1 * sc + bfh(b[1]));
  *(v2u*)(XCATB + (size_t)row * 96 + t * 2) = o;
}

// ------------------------------------- pipelined F=256 MFMA GEMM (T3+T4)
// 3-buffer LDS double-pipeline: per chunk c, wait vmcnt(G) (counted, never 0
// mid-loop), barrier, issue A-loads for c+1 and global_load_lds stage for
// c+2, then ds_read+MFMA chunk c. Fully unrolled -> all reg arrays static.
// Wave tile = 32 rows x 128 cols: each B-frag feeds 4 MFMAs (2 row-frags x
// hi/lo). Block = WAVES waves x 32 rows, 2 col-tiles per row-strip (grid x2).
template <int N_>
__device__ __forceinline__ void vwait() {
  if constexpr (N_ == 0)       asm volatile("s_waitcnt vmcnt(0)" ::: "memory");
  else if constexpr (N_ == 4)  asm volatile("s_waitcnt vmcnt(4)" ::: "memory");
  else if constexpr (N_ == 8)  asm volatile("s_waitcnt vmcnt(8)" ::: "memory");
  else if constexpr (N_ == 16) asm volatile("s_waitcnt vmcnt(16)" ::: "memory");
}

template <int K1, int K2, int WAVES>
__global__ __launch_bounds__(WAVES * 64, 3) void lin256_kernel(
    const uint16_t* __restrict__ X1, const uint16_t* __restrict__ W1h, const uint16_t* __restrict__ W1l,
    const uint16_t* __restrict__ X2, const uint16_t* __restrict__ W2h, const uint16_t* __restrict__ W2l,
    const float* __restrict__ bias, uint16_t* __restrict__ OUT,
    int out_ld, int N, int do_relu) {
  constexpr int NC1 = K1 / 32;
  constexpr int NC2 = (K2 > 0) ? K2 / 32 : 0;
  constexpr int NCH = NC1 + NC2;
  constexpr int PPW = 8 / WAVES;     // 1KB staging units per wave per array
  constexpr int G   = 2 * PPW;       // glls in flight per wave per stage
  __shared__ short sW[3][2][128][32];   // 48 KB: [buf][hi/lo][wrow][kcol-swz]

  int tid  = threadIdx.x;
  int wave = tid >> 6, lane = tid & 63;
  int r = lane & 15, q = lane >> 4;
  int ct = blockIdx.x & 1, rt = blockIdx.x >> 1;
  int wr0 = rt * (WAVES * 32) + wave * 32;
  int colbase = ct << 7;
  int colsw = (q ^ (r & 3)) << 3;
  int rw0 = min(wr0 + r, N - 1);
  int rw1 = min(wr0 + 16 + r, N - 1);

  v8s aT[2][2];
  v4f acc[2][8];
#pragma unroll
  for (int g = 0; g < 2; ++g)
#pragma unroll
    for (int f = 0; f < 8; ++f) acc[g][f] = (v4f){0.f, 0.f, 0.f, 0.f};

  auto loadAinto = [&](int cc, v8s& d0, v8s& d1) {
    const uint16_t* Xs = (K2 == 0 || cc < NC1) ? X1 : X2;
    const int Ks = (K2 == 0 || cc < NC1) ? K1 : K2;
    const int kk = (K2 == 0 || cc < NC1) ? cc : cc - NC1;
    d0 = *reinterpret_cast<const v8s*>(Xs + (size_t)rw0 * Ks + kk * 32 + q * 8);
    d1 = *reinterpret_cast<const v8s*>(Xs + (size_t)rw1 * Ks + kk * 32 + q * 8);
  };
  auto stageC = [&](int cn) {
    const uint16_t* bh = (K2 == 0 || cn < NC1)
        ? (W1h + (size_t)cn * 8192) : (W2h + (size_t)(cn - NC1) * 8192);
    const uint16_t* bl = (K2 == 0 || cn < NC1)
        ? (W1l + (size_t)cn * 8192) : (W2l + (size_t)(cn - NC1) * 8192);
    bh += colbase * 32 + lane * 8;
    bl += colbase * 32 + lane * 8;
    short* d = &sW[cn % 3][0][0][0];
#pragma unroll
    for (int pp = 0; pp < PPW; ++pp) {
      int p = wave + pp * WAVES;
      __builtin_amdgcn_global_load_lds((AS1CV)(bh + p * 512), (AS3V)(d + p * 512), 16, 0, 0);
      __builtin_amdgcn_global_load_lds((AS1CV)(bl + p * 512), (AS3V)(d + 4096 + p * 512), 16, 0, 0);
    }
  };

  loadAinto(0, aT[0][0], aT[0][1]);
  stageC(0);
  stageC(1);

#pragma unroll
  for (int c = 0; c < NCH; ++c) {
    if (c < NCH - 1) vwait<G>(); else vwait<0>();
    __builtin_amdgcn_s_barrier();
    asm volatile("" ::: "memory");
    __builtin_amdgcn_sched_barrier(0);
    if (c + 1 < NCH) loadAinto(c + 1, aT[(c + 1) & 1][0], aT[(c + 1) & 1][1]);
    if (c + 2 < NCH) stageC(c + 2);
    const short* bb = &sW[c % 3][0][0][0];
#pragma unroll
    for (int ft = 0; ft < 8; ++ft) {
      v8s bh = *reinterpret_cast<const v8s*>(bb + (ft * 16 + r) * 32 + colsw);
      v8s bl = *reinterpret_cast<const v8s*>(bb + 4096 + (ft * 16 + r) * 32 + colsw);
      acc[0][ft] = __builtin_amdgcn_mfma_f32_16x16x32_bf16(aT[c & 1][0], bh, acc[0][ft], 0, 0, 0);
      acc[0][ft] = __builtin_amdgcn_mfma_f32_16x16x32_bf16(aT[c & 1][0], bl, acc[0][ft], 0, 0, 0);
      acc[1][ft] = __builtin_amdgcn_mfma_f32_16x16x32_bf16(aT[c & 1][1], bh, acc[1][ft], 0, 0, 0);
      acc[1][ft] = __builtin_amdgcn_mfma_f32_16x16x32_bf16(aT[c & 1][1], bl, acc[1][ft], 0, 0, 0);
    }
  }

#pragma unroll
  for (int g = 0; g < 2; ++g)
#pragma unroll
    for (int ft = 0; ft < 8; ++ft) {
      int col = colbase + ft * 16 + r;
      float bv = bias ? bias[col] : 0.f;
#pragma unroll
      for (int i = 0; i < 4; ++i) {
        int row = wr0 + g * 16 + q * 4 + i;
        if (row < N) {
          float v = acc[g][ft][i] + bv;
          if (do_relu) v = fmaxf(v, 0.f);
          OUT[(size_t)row * out_ld + col] = rne16(v);
        }
      }
    }
}

// ------------------------------------- F=40 LDS row-strip GEMM (proven path)
template <int K1, int K2, int F, bool OUTBF>
__global__ __launch_bounds__(256, 4) void lin2b_kernel(
    const uint16_t* __restrict__ X1, const uint16_t* __restrict__ W1h, const uint16_t* __restrict__ W1l,
    const uint16_t* __restrict__ X2, const uint16_t* __restrict__ W2h, const uint16_t* __restrict__ W2l,
    const float* __restrict__ bias, const uint16_t* __restrict__ addin,
    void* __restrict__ OUTP, int out_ld, int N, int do_relu) {
  constexpr int FP  = (F + 15) & ~15;
  constexpr int NF  = FP / 16;
  constexpr int NC1 = K1 / 32;
  constexpr int NCH = (K1 + (K2 > 0 ? K2 : 0)) / 32;
  constexpr int RS  = 40;
  __shared__ short sW[2][FP][RS];

  int tid  = threadIdx.x;
  int wave = tid >> 6, lane = tid & 63;
  int r = lane & 15, q = lane >> 4;
  int row0 = blockIdx.x * 64 + wave * 16;
  int rowA = row0 + r; if (rowA > N - 1) rowA = N - 1;

  int srow = tid >> 2;
  int sj   = tid & 3;

  v4f acc[NF];
#pragma unroll
  for (int i = 0; i < NF; ++i) acc[i] = (v4f){0.f, 0.f, 0.f, 0.f};

  for (int c = 0; c < NCH; ++c) {
    const bool first = (K2 == 0) || (c < NC1);
    const uint16_t* Wh = first ? W1h : W2h;
    const uint16_t* Wl = first ? W1l : W2l;
    const uint16_t* Xs = first ? X1 : X2;
    const int K  = first ? K1 : K2;
    const int kc = (first ? c : c - NC1) * 32;

    if (c) __syncthreads();
    const v8s zz = {0, 0, 0, 0, 0, 0, 0, 0};
#pragma unroll
    for (int pass = 0; pass < (FP + 63) / 64; ++pass) {
      int row = srow + pass * 64;
      if (row < FP) {
        v8s hv = zz, lv = zz;
        if (row < F) {
          hv = *reinterpret_cast<const v8s*>(Wh + (size_t)row * K + kc + sj * 8);
          lv = *reinterpret_cast<const v8s*>(Wl + (size_t)row * K + kc + sj * 8);
        }
        *reinterpret_cast<v8s*>(&sW[0][row][sj * 8]) = hv;
        *reinterpret_cast<v8s*>(&sW[1][row][sj * 8]) = lv;
      }
    }
    v8s ah = *reinterpret_cast<const v8s*>(Xs + (size_t)rowA * K + kc + q * 8);
    __syncthreads();
#pragma unroll
    for (int ft = 0; ft < NF; ++ft) {
      v8s bh = *reinterpret_cast<const v8s*>(&sW[0][ft * 16 + r][q * 8]);
      v8s bl = *reinterpret_cast<const v8s*>(&sW[1][ft * 16 + r][q * 8]);
      acc[ft] = __builtin_amdgcn_mfma_f32_16x16x32_bf16(ah, bh, acc[ft], 0, 0, 0);
      acc[ft] = __builtin_amdgcn_mfma_f32_16x16x32_bf16(ah, bl, acc[ft], 0, 0, 0);
    }
  }

#pragma unroll
  for (int ft = 0; ft < NF; ++ft) {
    int col = ft * 16 + r;
    if (col < F) {
      float bv = bias ? bias[col] : 0.f;
#pragma unroll
      for (int i = 0; i < 4; ++i) {
        int row = row0 + q * 4 + i;
        if (row < N) {
          float v = acc[ft][i] + bv;
          if (addin) v += bfh(addin[(size_t)row * F + col]);
          if (do_relu) v = fmaxf(v, 0.f);
          size_t o = (size_t)row * out_ld + col;
          if (OUTBF) ((uint16_t*)OUTP)[o] = rne16(v);
          else ((float*)OUTP)[o] = v;
        }
      }
    }
  }
}

// Dual-output 40-col GEMM (K=256): OUT1 = X*W1^T, OUT2 = X*W2^T + b2.
__global__ __launch_bounds__(256, 4) void lin40ab_kernel(
    const uint16_t* __restrict__ X,
    const uint16_t* __restrict__ W1h, const uint16_t* __restrict__ W1l,
    const uint16_t* __restrict__ W2h, const uint16_t* __restrict__ W2l,
    const float* __restrict__ bias2,
    uint16_t* __restrict__ OUT1, uint16_t* __restrict__ OUT2, int N) {
  constexpr int K = 256, F = 40, FP = 48, NF = 3, RS = 40;
  __shared__ short sW[2][2][FP][RS];

  int tid  = threadIdx.x;
  int wave = tid >> 6, lane = tid & 63;
  int r = lane & 15, q = lane >> 4;
  int row0 = blockIdx.x * 64 + wave * 16;
  int rowA = row0 + r; if (rowA > N - 1) rowA = N - 1;
  int srow = tid >> 2, sj = tid & 3;

  v4f acc[2][NF];
#pragma unroll
  for (int w = 0; w < 2; ++w)
#pragma unroll
    for (int i = 0; i < NF; ++i) acc[w][i] = (v4f){0.f, 0.f, 0.f, 0.f};

  for (int c = 0; c < K / 32; ++c) {
    int kc = c * 32;
    if (c) __syncthreads();
    if (srow < FP) {
      const v8s zz = {0, 0, 0, 0, 0, 0, 0, 0};
      v8s a = zz, b = zz, cc = zz, d = zz;
      if (srow < F) {
        a  = *reinterpret_cast<const v8s*>(W1h + (size_t)srow * K + kc + sj * 8);
        b  = *reinterpret_cast<const v8s*>(W1l + (size_t)srow * K + kc + sj * 8);
        cc = *reinterpret_cast<const v8s*>(W2h + (size_t)srow * K + kc + sj * 8);
        d  = *reinterpret_cast<const v8s*>(W2l + (size_t)srow * K + kc + sj * 8);
      }
      *reinterpret_cast<v8s*>(&sW[0][0][srow][sj * 8]) = a;
      *reinterpret_cast<v8s*>(&sW[0][1][srow][sj * 8]) = b;
      *reinterpret_cast<v8s*>(&sW[1][0][srow][sj * 8]) = cc;
      *reinterpret_cast<v8s*>(&sW[1][1][srow][sj * 8]) = d;
    }
    v8s ah = *reinterpret_cast<const v8s*>(X + (size_t)rowA * K + kc + q * 8);
    __syncthreads();
#pragma unroll
    for (int w = 0; w < 2; ++w)
#pragma unroll
      for (int ft = 0; ft < NF; ++ft) {
        v8s bh = *reinterpret_cast<const v8s*>(&sW[w][0][ft * 16 + r][q * 8]);
        v8s bl = *reinterpret_cast<const v8s*>(&sW[w][1][ft * 16 + r][q * 8]);
        acc[w][ft] = __builtin_amdgcn_mfma_f32_16x16x32_bf16(ah, bh, acc[w][ft], 0, 0, 0);
        acc[w][ft] = __builtin_amdgcn_mfma_f32_16x16x32_bf16(ah, bl, acc[w][ft], 0, 0, 0);
      }
  }

#pragma unroll
  for (int ft = 0; ft < NF; ++ft) {
    int col = ft * 16 + r;
    if (col < F) {
      float bv = bias2[col];
#pragma unroll
      for (int i = 0; i < 4; ++i) {
        int row = row0 + q * 4 + i;
        if (row < N) {
          OUT1[(size_t)row * F + col] = rne16(acc[0][ft][i]);
          OUT2[(size_t)row * F + col] = rne16(acc[1][ft][i] + bv);
        }
      }
    }
  }
}

// ---------------- final: MFMA GEMM (K=96, F=40) + fused log-softmax
__global__ __launch_bounds__(256, 4) void final_mfma_kernel(
    const uint16_t* __restrict__ XB96,
    const uint16_t* __restrict__ Wh, const uint16_t* __restrict__ Wl,
    const float* __restrict__ lpb, float* __restrict__ out, int N) {
  constexpr int K = 96, F = 40, FP = 48, NF = 3, RS = 40;
  __shared__ short sW[2][FP][RS];

  int tid  = threadIdx.x;
  int wave = tid >> 6, lane = tid & 63;
  int r = lane & 15, q = lane >> 4;
  int row0 = blockIdx.x * 64 + wave * 16;
  int rowA = row0 + r; if (rowA > N - 1) rowA = N - 1;
  int srow = tid >> 2, sj = tid & 3;

  v4f acc[NF];
#pragma unroll
  for (int i = 0; i < NF; ++i) acc[i] = (v4f){0.f, 0.f, 0.f, 0.f};

  for (int c = 0; c < 3; ++c) {
    int kc = c * 32;
    if (c) __syncthreads();
    if (srow < FP) {
      const v8s zz = {0, 0, 0, 0, 0, 0, 0, 0};
      v8s hv = zz, lv = zz;
      if (srow < F) {
        hv = *reinterpret_cast<const v8s*>(Wh + (size_t)srow * K + kc + sj * 8);
        lv = *reinterpret_cast<const v8s*>(Wl + (size_t)srow * K + kc + sj * 8);
      }
      *reinterpret_cast<v8s*>(&sW[0][srow][sj * 8]) = hv;
      *reinterpret_cast<v8s*>(&sW[1][srow][sj * 8]) = lv;
    }
    v8s ah = *reinterpret_cast<const v8s*>(XB96 + (size_t)rowA * K + kc + q * 8);
    __syncthreads();
#pragma unroll
    for (int ft = 0; ft < NF; ++ft) {
      v8s bh = *reinterpret_cast<const v8s*>(&sW[0][ft * 16 + r][q * 8]);
      v8s bl = *reinterpret_cast<const v8s*>(&sW[1][ft * 16 + r][q * 8]);
      acc[ft] = __builtin_amdgcn_mfma_f32_16x16x32_bf16(ah, bh, acc[ft], 0, 0, 0);
      acc[ft] = __builtin_amdgcn_mfma_f32_16x16x32_bf16(ah, bl, acc[ft], 0, 0, 0);
    }
  }

  float b0 = lpb[r], b1 = lpb[16 + r];
  float b2 = (r < 8) ? lpb[32 + r] : 0.f;
#pragma unroll
  for (int i = 0; i < 4; ++i) {
    int row = row0 + q * 4 + i;
    float l0 = acc[0][i] + b0;
    float l1 = acc[1][i] + b1;
    float l2 = (r < 8) ? (acc[2][i] + b2) : -1e30f;
    float m = fmaxf(fmaxf(l0, l1), l2);
#pragma unroll
    for (int d = 1; d < 16; d <<= 1) m = fmaxf(m, __shfl_xor(m, d));
    float e = __expf(l0 - m) + __expf(l1 - m) + ((r < 8) ? __expf(l2 - m) : 0.f);
#pragma unroll
    for (int d = 1; d < 16; d <<= 1) e += __shfl_xor(e, d);
    if (row < N) {
      float ls = m + __logf(e);
      out[(size_t)row * 40 + r]      = l0 - ls;
      out[(size_t)row * 40 + 16 + r] = l1 - ls;
      if (r < 8) out[(size_t)row * 40 + 32 + r] = l2 - ls;
    }
  }
}

// ---------------------------------------------------------------- launcher
extern "C" void kernel_launch(void* const* d_in, const int* in_sizes, int n_in,
                              void* d_out, int out_size, void* d_ws, size_t ws_size,
                              hipStream_t stream) {
  const float* x      = (const float*)d_in[0];
  const int* src      = (const int*)d_in[1];
  const int* dst      = (const int*)d_in[2];
  const int* he_node  = (const int*)d_in[3];
  const int* he_edge  = (const int*)d_in[4];
  const float* s0wl = (const float*)d_in[5],  *s0wr = (const float*)d_in[6],  *s0b = (const float*)d_in[7];
  const float* s1wl = (const float*)d_in[8],  *s1wr = (const float*)d_in[9],  *s1b = (const float*)d_in[10];
  const float* s2wl = (const float*)d_in[11], *s2wr = (const float*)d_in[12], *s2b = (const float*)d_in[13];
  const float* h0w = (const float*)d_in[14], *h0b = (const float*)d_in[15];
  const float* h1w = (const float*)d_in[16], *h1b = (const float*)d_in[17];
  const float* h2w = (const float*)d_in[18], *h2b = (const float*)d_in[19];
  const float* h3w = (const float*)d_in[20], *h3b = (const float*)d_in[21];
  const float* h4w = (const float*)d_in[22], *h4b = (const float*)d_in[23];
  const float* lpw = (const float*)d_in[24], *lpb = (const float*)d_in[25];
  float* out = (float*)d_out;

  char* p = (char*)d_ws;
  auto carve = [&](size_t bytes) -> char* {
    char* r = p;
    p += (bytes + 255) & ~(size_t)255;
    return r;
  };
  int* adj_off  = (int*)carve((size_t)(N_NODES + 1) * 4);
  uint16_t* adj_src  = (uint16_t*)carve((size_t)N_EDGE * 2);
  int* heg_off  = (int*)carve((size_t)(N_HE + 1) * 4);
  uint16_t* heg_node = (uint16_t*)carve((size_t)N_INC * 2);
  int* hng_off  = (int*)carve((size_t)(N_NODES + 1) * 4);
  uint16_t* hng_edge = (uint16_t*)carve((size_t)N_INC * 2);
  int* gcnt     = (int*)carve((size_t)NBREL * 4);
  int* brel     = (int*)carve((size_t)NBREL * 4);
  int* gbb      = (int*)carve((size_t)278 * 4);
  uint32_t* stg_adj = (uint32_t*)carve((size_t)N_EDGE * 4);
  uint32_t* stg_heg = (uint32_t*)carve((size_t)N_INC * 4);
  uint32_t* stg_hng = (uint32_t*)carve((size_t)N_INC * 4);
  float* deg_inv = (float*)carve((size_t)N_NODES * 4);
  float* binv    = (float*)carve((size_t)N_HE * 4);
  float* dinv    = (float*)carve((size_t)N_NODES * 4);
  uint16_t* Wh = (uint16_t*)carve((size_t)W_TOTAL * 2);
  uint16_t* Wl = (uint16_t*)carve((size_t)W_TOTAL * 2);
  uint16_t* lpWh = (uint16_t*)carve((size_t)40 * 96 * 2);
  uint16_t* lpWl = (uint16_t*)carve((size_t)40 * 96 * 2);
  uint16_t* XB = (uint16_t*)carve((size_t)N_NODES * 128 * 2);
  uint16_t* U  = (uint16_t*)carve((size_t)N_NODES * 128 * 2);
  uint16_t* NA = (uint16_t*)carve((size_t)N_NODES * 256 * 2);
  uint16_t* NB_ = (uint16_t*)carve((size_t)N_NODES * 256 * 2);
  uint16_t* NC = (uint16_t*)carve((size_t)N_NODES * 256 * 2);
  uint16_t* EFa = (uint16_t*)carve((size_t)N_HE * 256 * 2);
  uint16_t* EFb = (uint16_t*)carve((size_t)N_HE * 256 * 2);
  uint16_t* T40 = (uint16_t*)carve((size_t)N_NODES * 40 * 2);
  uint16_t* T40B = (uint16_t*)carve((size_t)N_NODES * 40 * 2);
  uint16_t* T40H = (uint16_t*)carve((size_t)N_NODES * 40 * 2);
  uint16_t* XCATB = (uint16_t*)carve((size_t)N_NODES * 96 * 2);

  const int GL = (N_NODES + 63) / 64;              // F=40 row-strip grid
  const int GB = ((N_NODES + 127) / 128) * 2;      // 391*2 = 782, 256-thr
  const int GH = ((N_HE + 31) / 32) * 2;           // 157*2 = 314, 64-thr

  // ---- prep (zero + weight split + lpw split + x cvt) and binned CSR build
  prep_kernel<<<8052, 256, 0, stream>>>(gcnt, brel,
                                        s0wl, s0wr, s1wl, s1wr, s2wl, s2wr,
                                        h0w, h1w, h2w, h3w, h4w, Wh, Wl,
                                        lpw, lpWh, lpWl, x, XB);
  bhist_kernel<<<392, 256, 0, stream>>>(dst, he_edge, he_node, gcnt);
  bscan_kernel<<<1, 256, 0, stream>>>(gcnt, gbb, adj_off, heg_off, hng_off);
  binA_kernel<<<392, 256, 0, stream>>>(src, dst, he_node, he_edge,
                                       gbb, brel, stg_adj, stg_heg, stg_hng);
  binB2_kernel<<<275, 256, 0, stream>>>(gbb, stg_adj, stg_heg, stg_hng,
                                        adj_off, heg_off, hng_off,
                                        deg_inv, binv, dinv,
                                        adj_src, heg_node, hng_edge);

  // ---- merged layer-0 gathers (SAGE node-agg + hyper he-agg, both from XB)
  agg2b_kernel<128><<<N_NODES + N_HE, 64, 0, stream>>>(
      adj_off, adj_src, deg_inv, U, N_NODES,
      heg_off, heg_node, binv, EFa, XB);

  // ---- SAGE branch
  lin256_kernel<128, 128, 4><<<GB, 256, 0, stream>>>(
      U, Wh + 0, Wl + 0, XB, Wh + 32768, Wl + 32768, s0b, NA, 256, N_NODES, 1);
  aggb_kernel<256><<<N_NODES, 64, 0, stream>>>(adj_off, adj_src, deg_inv, NA, NB_, nullptr, 0);
  lin256_kernel<256, 256, 4><<<GB, 256, 0, stream>>>(
      NB_, Wh + 65536, Wl + 65536, NA, Wh + 131072, Wl + 131072, s1b, NC, 256, N_NODES, 1);
  lin40ab_kernel<<<GL, 256, 0, stream>>>(
      NC, Wh + 196608, Wl + 196608, Wh + 206848, Wl + 206848, s2b, T40, T40B, N_NODES);
  agg40s_kernel<<<N_NODES, 64, 0, stream>>>(adj_off, adj_src, deg_inv, T40, T40B, XCATB);

  // ---- Hypergraph branch: heagg -> tiny GEMM (5000 rows) -> nodeagg+bias+relu
  lin256_kernel<128, 0, 1><<<GH, 64, 0, stream>>>(
      EFa, Wh + 217088, Wl + 217088, nullptr, nullptr, nullptr, nullptr, EFb, 256, N_HE, 0);
  aggb_kernel<256><<<N_NODES, 64, 0, stream>>>(hng_off, hng_edge, dinv, EFb, NC, h0b, 1);

  aggb_kernel<256><<<N_HE, 64, 0, stream>>>(heg_off, heg_node, binv, NC, EFa, nullptr, 0);
  lin256_kernel<256, 0, 1><<<GH, 64, 0, stream>>>(
      EFa, Wh + 249856, Wl + 249856, nullptr, nullptr, nullptr, nullptr, EFb, 256, N_HE, 0);
  aggb_kernel<256><<<N_NODES, 64, 0, stream>>>(hng_off, hng_edge, dinv, EFb, NC, h1b, 1);

  aggb_kernel<256><<<N_HE, 64, 0, stream>>>(heg_off, heg_node, binv, NC, EFa, nullptr, 0);
  lin256_kernel<256, 0, 1><<<GH, 64, 0, stream>>>(
      EFa, Wh + 315392, Wl + 315392, nullptr, nullptr, nullptr, nullptr, EFb, 256, N_HE, 0);
  aggb_kernel<256><<<N_NODES, 64, 0, stream>>>(hng_off, hng_edge, dinv, EFb, NC, h2b, 1);

  aggb_kernel<256><<<N_HE, 64, 0, stream>>>(heg_off, heg_node, binv, NC, EFa, nullptr, 0);
  lin256_kernel<256, 0, 1><<<GH, 64, 0, stream>>>(
      EFa, Wh + 380928, Wl + 380928, nullptr, nullptr, nullptr, nullptr, EFb, 256, N_HE, 0);
  aggb_kernel<256><<<N_NODES, 64, 0, stream>>>(hng_off, hng_edge, dinv, EFb, NC, h3b, 1);

  // layer 4 (F=40): transform node features first, then two aggs
  lin2b_kernel<256, 0, 40, true><<<GL, 256, 0, stream>>>(
      NC, Wh + 446464, Wl + 446464, nullptr, nullptr, nullptr, nullptr, nullptr, T40H, 40, N_NODES, 0);
  aggb_kernel<40><<<N_HE, 64, 0, stream>>>(heg_off, heg_node, binv, T40H, EFa, nullptr, 0);
  agg40b_kernel<<<N_NODES, 64, 0, stream>>>(hng_off, hng_edge, dinv, EFa, h4b, XCATB);

  // ---- final MFMA linear + fused log_softmax
  final_mfma_kernel<<<GL, 256, 0, stream>>>(XCATB, lpWh, lpWl, lpb, out, N_NODES);
}

// Round 6
// 762.601 us; speedup vs baseline: 1.3823x; 1.0508x over previous
//
#include <hip/hip_runtime.h>
#include <hip/hip_bf16.h>
#include <cstdint>
#include <cstddef>

typedef __hip_bfloat16 bf16;
typedef short v8s __attribute__((ext_vector_type(8)));
typedef float v4f __attribute__((ext_vector_type(4)));
typedef unsigned short v8u __attribute__((ext_vector_type(8)));
typedef unsigned short v4u __attribute__((ext_vector_type(4)));
typedef unsigned short v2u __attribute__((ext_vector_type(2)));

#define N_NODES 50000
#define N_HE    5000
#define N_EDGE  800000
#define N_INC   400000
#define W_TOTAL 456704
#define NBREL   275   // 98 adj + 79 heg + 98 hng bucket cursors

#define AS1CV const __attribute__((address_space(1))) void*
#define AS3V  __attribute__((address_space(3))) void*

__device__ inline float bfh(uint32_t u) { return __uint_as_float(u << 16); }
__device__ inline uint16_t rne16(float f) {
  uint32_t u = __float_as_uint(f);
  return (uint16_t)((u + 0x7FFFu + ((u >> 16) & 1u)) >> 16);
}

// ---- prep: zero gcnt+brel + split weights (incl lpw, stride 96) + cvt x
// F=256 weight matrices are stored CHUNK-MAJOR + XOR-swizzled so that
// global_load_lds linear writes produce a bank-friendly LDS layout:
//   element w[row][c*32 + q*8 + e] -> idx c*8192 + row*32 + ((q^(row&3))<<3) + e
// F=40 matrices (s2wl/s2wr/h4w) stay row-major (old LDS path).
__global__ void prep_kernel(int* gcnt, int* brel,
                            const float* s0wl, const float* s0wr,
                            const float* s1wl, const float* s1wr,
                            const float* s2wl, const float* s2wr,
                            const float* h0w, const float* h1w,
                            const float* h2w, const float* h3w, const float* h4w,
                            uint16_t* hi, uint16_t* lo,
                            const float* lpw, uint16_t* lpWh, uint16_t* lpWl,
                            const float* X, uint16_t* XB) {
  int b = blockIdx.x;
  if (b < 3) {
    int i = b * 256 + threadIdx.x;
    if (i < NBREL) gcnt[i] = 0;
    else if (i < 2 * NBREL) brel[i - NBREL] = 0;
    return;
  }
  if (b < 1787) {
    int i = (b - 3) * 256 + threadIdx.x;
    if (i >= W_TOTAL) return;
    const float* src; int base; int kln2; int sw;
    if (i < 32768)       { src = s0wl; base = 0;      kln2 = 7; sw = 1; }
    else if (i < 65536)  { src = s0wr; base = 32768;  kln2 = 7; sw = 1; }
    else if (i < 131072) { src = s1wl; base = 65536;  kln2 = 8; sw = 1; }
    else if (i < 196608) { src = s1wr; base = 131072; kln2 = 8; sw = 1; }
    else if (i < 206848) { src = s2wl; base = 196608; kln2 = 8; sw = 0; }
    else if (i < 217088) { src = s2wr; base = 206848; kln2 = 8; sw = 0; }
    else if (i < 249856) { src = h0w;  base = 217088; kln2 = 7; sw = 1; }
    else if (i < 315392) { src = h1w;  base = 249856; kln2 = 8; sw = 1; }
    else if (i < 380928) { src = h2w;  base = 315392; kln2 = 8; sw = 1; }
    else if (i < 446464) { src = h3w;  base = 380928; kln2 = 8; sw = 1; }
    else                 { src = h4w;  base = 446464; kln2 = 8; sw = 0; }
    int j = i - base;
    float v = src[j];
    int nj = j;
    if (sw) {
      int row = j >> kln2;
      int col = j & ((1 << kln2) - 1);
      int c = col >> 5, qq = (col >> 3) & 3, e = col & 7;
      nj = c * 8192 + row * 32 + ((qq ^ (row & 3)) << 3) + e;
    }
    uint16_t hb = rne16(v);
    hi[base + nj] = hb;
    lo[base + nj] = rne16(v - bfh(hb));
    return;
  }
  if (b < 1802) {
    int i = (b - 1787) * 256 + threadIdx.x;   // 40 rows x 96 cols
    if (i >= 40 * 96) return;
    int row = i / 96, col = i - row * 96;
    float v = (col < 80) ? lpw[row * 80 + col] : 0.f;
    uint16_t hb = rne16(v);
    lpWh[i] = hb;
    lpWl[i] = rne16(v - bfh(hb));
    return;
  }
  {
    int i = (b - 1802) * 256 + threadIdx.x;   // v4 index
    if (i >= N_NODES * 32) return;
    v4f v = *((const v4f*)X + i);
    v4u o;
    o[0] = rne16(v[0]); o[1] = rne16(v[1]); o[2] = rne16(v[2]); o[3] = rne16(v[3]);
    *((v4u*)XB + i) = o;
  }
}

// ---------------- bucket-level histogram (LDS-local; replaces hist_kernel)
template <int NB, int SH>
__device__ inline void bhist_section(const int* __restrict__ key_arr, int n, int blk,
                                     int* __restrict__ gcnt) {
  __shared__ int h[128];
  int t = threadIdx.x;
  for (int k = t; k < NB; k += 256) h[k] = 0;
  __syncthreads();
  int e0 = blk * 4096;
  int cnt = min(4096, n - e0);
  for (int k = t; k < cnt; k += 256) atomicAdd(&h[key_arr[e0 + k] >> SH], 1);
  __syncthreads();
  for (int k = t; k < NB; k += 256) atomicAdd(&gcnt[k], h[k]);
}

__global__ __launch_bounds__(256) void bhist_kernel(
    const int* __restrict__ dst, const int* __restrict__ he_edge,
    const int* __restrict__ he_node, int* gcnt) {
  int b = blockIdx.x;
  if (b < 196)      bhist_section<98, 9>(dst, N_EDGE, b, gcnt);
  else if (b < 294) bhist_section<79, 6>(he_edge, N_INC, b - 196, gcnt + 98);
  else              bhist_section<98, 9>(he_node, N_INC, b - 294, gcnt + 177);
}

// ---------------- bucket-base scan (one wave per section) + CSR sentinels
__global__ void bscan_kernel(const int* __restrict__ gcnt, int* gbb,
                             int* adj_off, int* heg_off, int* hng_off) {
  int t = threadIdx.x;
  if (t == 0)        { int s = 0; for (int b = 0; b < 98; ++b) { gbb[b] = s; s += gcnt[b]; } gbb[98] = s; }
  else if (t == 64)  { int s = 0; for (int b = 0; b < 79; ++b) { gbb[99 + b] = s; s += gcnt[98 + b]; } gbb[99 + 79] = s; }
  else if (t == 128) { int s = 0; for (int b = 0; b < 98; ++b) { gbb[179 + b] = s; s += gcnt[177 + b]; } gbb[179 + 98] = s; }
  else if (t == 192) { adj_off[N_NODES] = N_EDGE; heg_off[N_HE] = N_INC; hng_off[N_NODES] = N_INC; }
}

// ---------------- binned two-phase fill (no scatter write amplification)
template <int NB, int SH>
__device__ inline void binA_section(const int* __restrict__ key_arr,
                                    const int* __restrict__ pay_arr, int n, int blk,
                                    const int* __restrict__ bb,
                                    int* brel, uint32_t* __restrict__ stg) {
  __shared__ int lcnt[128], lscan[128], lcnt2[128], gbase[128];
  __shared__ uint32_t sstage[4096];
  int t = threadIdx.x;
  int e0 = blk * 4096;
  int cnt = min(4096, n - e0);
  for (int k = t; k < NB; k += 256) { lcnt[k] = 0; lcnt2[k] = 0; }
  __syncthreads();
  for (int k = t; k < cnt; k += 256) atomicAdd(&lcnt[key_arr[e0 + k] >> SH], 1);
  __syncthreads();
  if (t == 0) {
    int s = 0;
    for (int b = 0; b < NB; ++b) { lscan[b] = s; s += lcnt[b]; }
  }
  __syncthreads();
  if (t < NB) gbase[t] = bb[t] + atomicAdd(&brel[t], lcnt[t]);
  __syncthreads();
  for (int k = t; k < cnt; k += 256) {
    int key = key_arr[e0 + k];
    int pay = pay_arr[e0 + k];
    int b = key >> SH;
    int r = atomicAdd(&lcnt2[b], 1);
    sstage[lscan[b] + r] = ((uint32_t)pay << 16) | (uint32_t)key;
  }
  __syncthreads();
  for (int b = 0; b < NB; ++b) {
    int len = lcnt[b], ls = lscan[b], gb = gbase[b];
    for (int k = t; k < len; k += 256) stg[gb + k] = sstage[ls + k];
  }
}

__global__ __launch_bounds__(256) void binA_kernel(
    const int* __restrict__ src, const int* __restrict__ dst,
    const int* __restrict__ he_node, const int* __restrict__ he_edge,
    const int* __restrict__ gbb, int* brel,
    uint32_t* stg_adj, uint32_t* stg_heg, uint32_t* stg_hng) {
  int b = blockIdx.x;
  if (b < 196)      binA_section<98, 9>(dst, src, N_EDGE, b, gbb, brel, stg_adj);
  else if (b < 294) binA_section<79, 6>(he_edge, he_node, N_INC, b - 196, gbb + 99, brel + 98, stg_heg);
  else              binA_section<98, 9>(he_node, he_edge, N_INC, b - 294, gbb + 179, brel + 177, stg_hng);
}

// Pass B + per-node count/scan: writes CSR offsets, reciprocal scales, payloads.
template <int BS, int SH, int MODE>
__device__ inline void binB2_section(int bkt, const int* __restrict__ bb, int nkeys,
                                     const uint32_t* __restrict__ stg,
                                     int* __restrict__ off_out,
                                     float* __restrict__ scl,
                                     uint16_t* __restrict__ out) {
  __shared__ int lcnt[512], loff[512], lcur[512];
  __shared__ int ws[4];
  int t = threadIdx.x;
  int nb0 = bkt << SH;
  int nb1 = min(nb0 + BS, nkeys);
  int nn = nb1 - nb0;
  int e0 = bb[bkt], e1 = bb[bkt + 1];
  for (int k = t; k < nn; k += 256) lcnt[k] = 0;
  __syncthreads();
  for (int e = e0 + t; e < e1; e += 256)
    atomicAdd(&lcnt[(int)(stg[e] & 0xFFFFu) - nb0], 1);
  __syncthreads();
  // exclusive scan over nn counts (2 per thread, shfl within wave, 4 waves)
  int lane = t & 63, wv = t >> 6;
  int i0 = 2 * t;
  int a0 = (i0 < nn) ? lcnt[i0] : 0;
  int a1 = (i0 + 1 < nn) ? lcnt[i0 + 1] : 0;
  int ts = a0 + a1;
  int val = ts;
#pragma unroll
  for (int d = 1; d < 64; d <<= 1) {
    int x = __shfl_up(val, d);
    if (lane >= d) val += x;
  }
  if (lane == 63) ws[wv] = val;
  __syncthreads();
  if (t == 0) {
    int s = 0;
#pragma unroll
    for (int w = 0; w < 4; ++w) { int v = ws[w]; ws[w] = s; s += v; }
  }
  __syncthreads();
  int excl = ws[wv] + (val - ts);
  if (i0 < nn) loff[i0] = excl;
  if (i0 + 1 < nn) loff[i0 + 1] = excl + a0;
  __syncthreads();
  for (int k = t; k < nn; k += 256) {
    int base = e0 + loff[k];
    off_out[nb0 + k] = base;
    lcur[k] = base;
    int c = lcnt[k];
    scl[nb0 + k] = (MODE == 0) ? 1.0f / (float)(c > 1 ? c : 1)
                               : (c > 0 ? 1.0f / (float)c : 0.f);
  }
  __syncthreads();
  for (int e = e0 + t; e < e1; e += 256) {
    uint32_t v = stg[e];
    int key = (int)(v & 0xFFFFu);
    int p = atomicAdd(&lcur[key - nb0], 1);
    out[p] = (uint16_t)(v >> 16);
  }
}

__global__ __launch_bounds__(256) void binB2_kernel(
    const int* __restrict__ gbb,
    const uint32_t* __restrict__ stg_adj, const uint32_t* __restrict__ stg_heg,
    const uint32_t* __restrict__ stg_hng,
    int* adj_off, int* heg_off, int* hng_off,
    float* deg_inv, float* binv, float* dinv,
    uint16_t* adj_src, uint16_t* heg_node, uint16_t* hng_edge) {
  int b = blockIdx.x;
  if (b < 98)       binB2_section<512, 9, 0>(b, gbb, N_NODES, stg_adj, adj_off, deg_inv, adj_src);
  else if (b < 177) binB2_section<64, 6, 1>(b - 98, gbb + 99, N_HE, stg_heg, heg_off, binv, heg_node);
  else              binB2_section<512, 9, 1>(b - 177, gbb + 179, N_NODES, stg_hng, hng_off, dinv, hng_edge);
}

// ------------------------------- gather-mean row body (uint16 CSR idx)
template <int F>
__device__ inline void agg_row(const int* __restrict__ off, const uint16_t* __restrict__ idx,
                               const float* __restrict__ scale,
                               const uint16_t* __restrict__ X,
                               uint16_t* __restrict__ OUT, int row,
                               const float* __restrict__ bias, int do_relu) {
  constexpr int VEC = (F >= 256) ? 4 : 2;
  int t = threadIdx.x;
  if (t * VEC >= F) return;
  int j0 = off[row], j1 = off[row + 1];
  float sc = scale[row];
  float acc[VEC];
#pragma unroll
  for (int k = 0; k < VEC; ++k) acc[k] = 0.f;

  int j = j0;
  for (; j + 7 < j1; j += 8) {
    int s[8];
#pragma unroll
    for (int u = 0; u < 8; ++u) s[u] = idx[j + u];
    if (VEC == 4) {
      v4u v[8];
#pragma unroll
      for (int u = 0; u < 8; ++u) v[u] = *(const v4u*)(X + (size_t)s[u] * F + t * 4);
#pragma unroll
      for (int u = 0; u < 8; ++u)
#pragma unroll
        for (int k = 0; k < 4; ++k) acc[k] += bfh(v[u][k]);
    } else {
      v2u v[8];
#pragma unroll
      for (int u = 0; u < 8; ++u) v[u] = *(const v2u*)(X + (size_t)s[u] * F + t * 2);
#pragma unroll
      for (int u = 0; u < 8; ++u)
#pragma unroll
        for (int k = 0; k < 2; ++k) acc[k] += bfh(v[u][k]);
    }
  }
  for (; j < j1; ++j) {
    int s = idx[j];
    if (VEC == 4) {
      v4u a = *(const v4u*)(X + (size_t)s * F + t * 4);
#pragma unroll
      for (int k = 0; k < 4; ++k) acc[k] += bfh(a[k]);
    } else {
      v2u a = *(const v2u*)(X + (size_t)s * F + t * 2);
#pragma unroll
      for (int k = 0; k < 2; ++k) acc[k] += bfh(a[k]);
    }
  }

  if (VEC == 4) {
    v4u o;
#pragma unroll
    for (int k = 0; k < 4; ++k) {
      float v = acc[k] * sc;
      if (bias) { v += bias[t * 4 + k]; if (do_relu) v = fmaxf(v, 0.f); }
      o[k] = rne16(v);
    }
    *(v4u*)(OUT + (size_t)row * F + t * 4) = o;
  } else {
    v2u o;
#pragma unroll
    for (int k = 0; k < 2; ++k) {
      float v = acc[k] * sc;
      if (bias) { v += bias[t * 2 + k]; if (do_relu) v = fmaxf(v, 0.f); }
      o[k] = rne16(v);
    }
    *(v2u*)(OUT + (size_t)row * F + t * 2) = o;
  }
}

template <int F>
__global__ void aggb_kernel(const int* __restrict__ off, const uint16_t* __restrict__ idx,
                            const float* __restrict__ scale,
                            const uint16_t* __restrict__ X,
                            uint16_t* __restrict__ OUT,
                            const float* __restrict__ bias, int do_relu) {
  agg_row<F>(off, idx, scale, X, OUT, blockIdx.x, bias, do_relu);
}

template <int F>
__global__ void agg2b_kernel(const int* __restrict__ off1, const uint16_t* __restrict__ idx1,
                             const float* __restrict__ sc1, uint16_t* __restrict__ OUT1, int n1,
                             const int* __restrict__ off2, const uint16_t* __restrict__ idx2,
                             const float* __restrict__ sc2, uint16_t* __restrict__ OUT2,
                             const uint16_t* __restrict__ X) {
  int row = blockIdx.x;
  if (row < n1) agg_row<F>(off1, idx1, sc1, X, OUT1, row, nullptr, 0);
  else          agg_row<F>(off2, idx2, sc2, X, OUT2, row - n1, nullptr, 0);
}

// Hyper tail: XCATB[:,40:80] = bf16(dinv*agg(EF40) + bias); zeros pad 80:96.
// 8-wide edge batching (agg_row pattern) for memory-level parallelism.
__global__ void agg40b_kernel(const int* __restrict__ off, const uint16_t* __restrict__ idx,
                              const float* __restrict__ scale,
                              const uint16_t* __restrict__ EF40,
                              const float* __restrict__ bias,
                              uint16_t* __restrict__ XCATB) {
  int row = blockIdx.x;
  int t = threadIdx.x;
  if (t < 8) {
    v2u z = {0, 0};
    *(v2u*)(XCATB + (size_t)row * 96 + 80 + t * 2) = z;
  }
  if (t >= 20) return;
  int j0 = off[row], j1 = off[row + 1];
  float sc = scale[row];
  float a0 = 0.f, a1 = 0.f;
  int j = j0;
  for (; j + 7 < j1; j += 8) {
    int s[8];
#pragma unroll
    for (int u = 0; u < 8; ++u) s[u] = idx[j + u];
    v2u v[8];
#pragma unroll
    for (int u = 0; u < 8; ++u) v[u] = *(const v2u*)(EF40 + (size_t)s[u] * 40 + t * 2);
#pragma unroll
    for (int u = 0; u < 8; ++u) { a0 += bfh(v[u][0]); a1 += bfh(v[u][1]); }
  }
  for (; j < j1; ++j) {
    int s = idx[j];
    v2u v = *(const v2u*)(EF40 + (size_t)s * 40 + t * 2);
    a0 += bfh(v[0]);
    a1 += bfh(v[1]);
  }
  v2u o;
  o[0] = rne16(a0 * sc + bias[t * 2]);
  o[1] = rne16(a1 * sc + bias[t * 2 + 1]);
  *(v2u*)(XCATB + (size_t)row * 96 + 40 + t * 2) = o;
}

// SAGE tail: XCATB[:, :40] = bf16(deg_inv*agg(T40a) + T40b)
// 8-wide edge batching (agg_row pattern) for memory-level parallelism.
__global__ void agg40s_kernel(const int* __restrict__ off, const uint16_t* __restrict__ idx,
                              const float* __restrict__ scale,
                              const uint16_t* __restrict__ T40a,
                              const uint16_t* __restrict__ T40b,
                              uint16_t* __restrict__ XCATB) {
  int row = blockIdx.x;
  int t = threadIdx.x;
  if (t >= 20) return;
  int j0 = off[row], j1 = off[row + 1];
  float sc = scale[row];
  float a0 = 0.f, a1 = 0.f;
  int j = j0;
  for (; j + 7 < j1; j += 8) {
    int s[8];
#pragma unroll
    for (int u = 0; u < 8; ++u) s[u] = idx[j + u];
    v2u v[8];
#pragma unroll
    for (int u = 0; u < 8; ++u) v[u] = *(const v2u*)(T40a + (size_t)s[u] * 40 + t * 2);
#pragma unroll
    for (int u = 0; u < 8; ++u) { a0 += bfh(v[u][0]); a1 += bfh(v[u][1]); }
  }
  for (; j < j1; ++j) {
    int s = idx[j];
    v2u v = *(const v2u*)(T40a + (size_t)s * 40 + t * 2);
    a0 += bfh(v[0]);
    a1 += bfh(v[1]);
  }
  v2u b = *(const v2u*)(T40b + (size_t)row * 40 + t * 2);
  v2u o;
  o[0] = rne16(a0 * sc + bfh(b[0]));
  o[1] = rne16(a1 * sc + bfh(b[1]));
  *(v2u*)(XCATB + (size_t)row * 96 + t * 2) = o;
}

// ------------------------------------- pipelined F=256 MFMA GEMM (T3+T4)
// 3-buffer LDS double-pipeline: per chunk c, wait vmcnt(G) (counted, never 0
// mid-loop), barrier, issue A-loads for c+1 and global_load_lds stage for
// c+2, then ds_read+MFMA chunk c. Fully unrolled -> all reg arrays static.
// Wave tile = 32 rows x 128 cols: each B-frag feeds 4 MFMAs (2 row-frags x
// hi/lo). Block = WAVES waves x 32 rows, 2 col-tiles per row-strip (grid x2).
template <int N_>
__device__ __forceinline__ void vwait() {
  if constexpr (N_ == 0)       asm volatile("s_waitcnt vmcnt(0)" ::: "memory");
  else if constexpr (N_ == 4)  asm volatile("s_waitcnt vmcnt(4)" ::: "memory");
  else if constexpr (N_ == 8)  asm volatile("s_waitcnt vmcnt(8)" ::: "memory");
  else if constexpr (N_ == 16) asm volatile("s_waitcnt vmcnt(16)" ::: "memory");
}

template <int K1, int K2, int WAVES>
__global__ __launch_bounds__(WAVES * 64, 3) void lin256_kernel(
    const uint16_t* __restrict__ X1, const uint16_t* __restrict__ W1h, const uint16_t* __restrict__ W1l,
    const uint16_t* __restrict__ X2, const uint16_t* __restrict__ W2h, const uint16_t* __restrict__ W2l,
    const float* __restrict__ bias, uint16_t* __restrict__ OUT,
    int out_ld, int N, int do_relu) {
  constexpr int NC1 = K1 / 32;
  constexpr int NC2 = (K2 > 0) ? K2 / 32 : 0;
  constexpr int NCH = NC1 + NC2;
  constexpr int PPW = 8 / WAVES;     // 1KB staging units per wave per array
  constexpr int G   = 2 * PPW;       // glls in flight per wave per stage
  __shared__ short sW[3][2][128][32];   // 48 KB: [buf][hi/lo][wrow][kcol-swz]

  int tid  = threadIdx.x;
  int wave = tid >> 6, lane = tid & 63;
  int r = lane & 15, q = lane >> 4;
  int ct = blockIdx.x & 1, rt = blockIdx.x >> 1;
  int wr0 = rt * (WAVES * 32) + wave * 32;
  int colbase = ct << 7;
  int colsw = (q ^ (r & 3)) << 3;
  int rw0 = min(wr0 + r, N - 1);
  int rw1 = min(wr0 + 16 + r, N - 1);

  v8s aT[2][2];
  v4f acc[2][8];
#pragma unroll
  for (int g = 0; g < 2; ++g)
#pragma unroll
    for (int f = 0; f < 8; ++f) acc[g][f] = (v4f){0.f, 0.f, 0.f, 0.f};

  auto loadAinto = [&](int cc, v8s& d0, v8s& d1) {
    const uint16_t* Xs = (K2 == 0 || cc < NC1) ? X1 : X2;
    const int Ks = (K2 == 0 || cc < NC1) ? K1 : K2;
    const int kk = (K2 == 0 || cc < NC1) ? cc : cc - NC1;
    d0 = *reinterpret_cast<const v8s*>(Xs + (size_t)rw0 * Ks + kk * 32 + q * 8);
    d1 = *reinterpret_cast<const v8s*>(Xs + (size_t)rw1 * Ks + kk * 32 + q * 8);
  };
  auto stageC = [&](int cn) {
    const uint16_t* bh = (K2 == 0 || cn < NC1)
        ? (W1h + (size_t)cn * 8192) : (W2h + (size_t)(cn - NC1) * 8192);
    const uint16_t* bl = (K2 == 0 || cn < NC1)
        ? (W1l + (size_t)cn * 8192) : (W2l + (size_t)(cn - NC1) * 8192);
    bh += colbase * 32 + lane * 8;
    bl += colbase * 32 + lane * 8;
    short* d = &sW[cn % 3][0][0][0];
#pragma unroll
    for (int pp = 0; pp < PPW; ++pp) {
      int p = wave + pp * WAVES;
      __builtin_amdgcn_global_load_lds((AS1CV)(bh + p * 512), (AS3V)(d + p * 512), 16, 0, 0);
      __builtin_amdgcn_global_load_lds((AS1CV)(bl + p * 512), (AS3V)(d + 4096 + p * 512), 16, 0, 0);
    }
  };

  loadAinto(0, aT[0][0], aT[0][1]);
  stageC(0);
  stageC(1);

#pragma unroll
  for (int c = 0; c < NCH; ++c) {
    if (c < NCH - 1) vwait<G>(); else vwait<0>();
    __builtin_amdgcn_s_barrier();
    asm volatile("" ::: "memory");
    __builtin_amdgcn_sched_barrier(0);
    if (c + 1 < NCH) loadAinto(c + 1, aT[(c + 1) & 1][0], aT[(c + 1) & 1][1]);
    if (c + 2 < NCH) stageC(c + 2);
    const short* bb = &sW[c % 3][0][0][0];
#pragma unroll
    for (int ft = 0; ft < 8; ++ft) {
      v8s bh = *reinterpret_cast<const v8s*>(bb + (ft * 16 + r) * 32 + colsw);
      v8s bl = *reinterpret_cast<const v8s*>(bb + 4096 + (ft * 16 + r) * 32 + colsw);
      acc[0][ft] = __builtin_amdgcn_mfma_f32_16x16x32_bf16(aT[c & 1][0], bh, acc[0][ft], 0, 0, 0);
      acc[0][ft] = __builtin_amdgcn_mfma_f32_16x16x32_bf16(aT[c & 1][0], bl, acc[0][ft], 0, 0, 0);
      acc[1][ft] = __builtin_amdgcn_mfma_f32_16x16x32_bf16(aT[c & 1][1], bh, acc[1][ft], 0, 0, 0);
      acc[1][ft] = __builtin_amdgcn_mfma_f32_16x16x32_bf16(aT[c & 1][1], bl, acc[1][ft], 0, 0, 0);
    }
  }

#pragma unroll
  for (int g = 0; g < 2; ++g)
#pragma unroll
    for (int ft = 0; ft < 8; ++ft) {
      int col = colbase + ft * 16 + r;
      float bv = bias ? bias[col] : 0.f;
#pragma unroll
      for (int i = 0; i < 4; ++i) {
        int row = wr0 + g * 16 + q * 4 + i;
        if (row < N) {
          float v = acc[g][ft][i] + bv;
          if (do_relu) v = fmaxf(v, 0.f);
          OUT[(size_t)row * out_ld + col] = rne16(v);
        }
      }
    }
}

// ------------------------------------- F=40 LDS row-strip GEMM (proven path)
template <int K1, int K2, int F, bool OUTBF>
__global__ __launch_bounds__(256, 4) void lin2b_kernel(
    const uint16_t* __restrict__ X1, const uint16_t* __restrict__ W1h, const uint16_t* __restrict__ W1l,
    const uint16_t* __restrict__ X2, const uint16_t* __restrict__ W2h, const uint16_t* __restrict__ W2l,
    const float* __restrict__ bias, const uint16_t* __restrict__ addin,
    void* __restrict__ OUTP, int out_ld, int N, int do_relu) {
  constexpr int FP  = (F + 15) & ~15;
  constexpr int NF  = FP / 16;
  constexpr int NC1 = K1 / 32;
  constexpr int NCH = (K1 + (K2 > 0 ? K2 : 0)) / 32;
  constexpr int RS  = 40;
  __shared__ short sW[2][FP][RS];

  int tid  = threadIdx.x;
  int wave = tid >> 6, lane = tid & 63;
  int r = lane & 15, q = lane >> 4;
  int row0 = blockIdx.x * 64 + wave * 16;
  int rowA = row0 + r; if (rowA > N - 1) rowA = N - 1;

  int srow = tid >> 2;
  int sj   = tid & 3;

  v4f acc[NF];
#pragma unroll
  for (int i = 0; i < NF; ++i) acc[i] = (v4f){0.f, 0.f, 0.f, 0.f};

  for (int c = 0; c < NCH; ++c) {
    const bool first = (K2 == 0) || (c < NC1);
    const uint16_t* Wh = first ? W1h : W2h;
    const uint16_t* Wl = first ? W1l : W2l;
    const uint16_t* Xs = first ? X1 : X2;
    const int K  = first ? K1 : K2;
    const int kc = (first ? c : c - NC1) * 32;

    if (c) __syncthreads();
    const v8s zz = {0, 0, 0, 0, 0, 0, 0, 0};
#pragma unroll
    for (int pass = 0; pass < (FP + 63) / 64; ++pass) {
      int row = srow + pass * 64;
      if (row < FP) {
        v8s hv = zz, lv = zz;
        if (row < F) {
          hv = *reinterpret_cast<const v8s*>(Wh + (size_t)row * K + kc + sj * 8);
          lv = *reinterpret_cast<const v8s*>(Wl + (size_t)row * K + kc + sj * 8);
        }
        *reinterpret_cast<v8s*>(&sW[0][row][sj * 8]) = hv;
        *reinterpret_cast<v8s*>(&sW[1][row][sj * 8]) = lv;
      }
    }
    v8s ah = *reinterpret_cast<const v8s*>(Xs + (size_t)rowA * K + kc + q * 8);
    __syncthreads();
#pragma unroll
    for (int ft = 0; ft < NF; ++ft) {
      v8s bh = *reinterpret_cast<const v8s*>(&sW[0][ft * 16 + r][q * 8]);
      v8s bl = *reinterpret_cast<const v8s*>(&sW[1][ft * 16 + r][q * 8]);
      acc[ft] = __builtin_amdgcn_mfma_f32_16x16x32_bf16(ah, bh, acc[ft], 0, 0, 0);
      acc[ft] = __builtin_amdgcn_mfma_f32_16x16x32_bf16(ah, bl, acc[ft], 0, 0, 0);
    }
  }

#pragma unroll
  for (int ft = 0; ft < NF; ++ft) {
    int col = ft * 16 + r;
    if (col < F) {
      float bv = bias ? bias[col] : 0.f;
#pragma unroll
      for (int i = 0; i < 4; ++i) {
        int row = row0 + q * 4 + i;
        if (row < N) {
          float v = acc[ft][i] + bv;
          if (addin) v += bfh(addin[(size_t)row * F + col]);
          if (do_relu) v = fmaxf(v, 0.f);
          size_t o = (size_t)row * out_ld + col;
          if (OUTBF) ((uint16_t*)OUTP)[o] = rne16(v);
          else ((float*)OUTP)[o] = v;
        }
      }
    }
  }
}

// Dual-output 40-col GEMM (K=256): OUT1 = X*W1^T, OUT2 = X*W2^T + b2.
__global__ __launch_bounds__(256, 4) void lin40ab_kernel(
    const uint16_t* __restrict__ X,
    const uint16_t* __restrict__ W1h, const uint16_t* __restrict__ W1l,
    const uint16_t* __restrict__ W2h, const uint16_t* __restrict__ W2l,
    const float* __restrict__ bias2,
    uint16_t* __restrict__ OUT1, uint16_t* __restrict__ OUT2, int N) {
  constexpr int K = 256, F = 40, FP = 48, NF = 3, RS = 40;
  __shared__ short sW[2][2][FP][RS];

  int tid  = threadIdx.x;
  int wave = tid >> 6, lane = tid & 63;
  int r = lane & 15, q = lane >> 4;
  int row0 = blockIdx.x * 64 + wave * 16;
  int rowA = row0 + r; if (rowA > N - 1) rowA = N - 1;
  int srow = tid >> 2, sj = tid & 3;

  v4f acc[2][NF];
#pragma unroll
  for (int w = 0; w < 2; ++w)
#pragma unroll
    for (int i = 0; i < NF; ++i) acc[w][i] = (v4f){0.f, 0.f, 0.f, 0.f};

  for (int c = 0; c < K / 32; ++c) {
    int kc = c * 32;
    if (c) __syncthreads();
    if (srow < FP) {
      const v8s zz = {0, 0, 0, 0, 0, 0, 0, 0};
      v8s a = zz, b = zz, cc = zz, d = zz;
      if (srow < F) {
        a  = *reinterpret_cast<const v8s*>(W1h + (size_t)srow * K + kc + sj * 8);
        b  = *reinterpret_cast<const v8s*>(W1l + (size_t)srow * K + kc + sj * 8);
        cc = *reinterpret_cast<const v8s*>(W2h + (size_t)srow * K + kc + sj * 8);
        d  = *reinterpret_cast<const v8s*>(W2l + (size_t)srow * K + kc + sj * 8);
      }
      *reinterpret_cast<v8s*>(&sW[0][0][srow][sj * 8]) = a;
      *reinterpret_cast<v8s*>(&sW[0][1][srow][sj * 8]) = b;
      *reinterpret_cast<v8s*>(&sW[1][0][srow][sj * 8]) = cc;
      *reinterpret_cast<v8s*>(&sW[1][1][srow][sj * 8]) = d;
    }
    v8s ah = *reinterpret_cast<const v8s*>(X + (size_t)rowA * K + kc + q * 8);
    __syncthreads();
#pragma unroll
    for (int w = 0; w < 2; ++w)
#pragma unroll
      for (int ft = 0; ft < NF; ++ft) {
        v8s bh = *reinterpret_cast<const v8s*>(&sW[w][0][ft * 16 + r][q * 8]);
        v8s bl = *reinterpret_cast<const v8s*>(&sW[w][1][ft * 16 + r][q * 8]);
        acc[w][ft] = __builtin_amdgcn_mfma_f32_16x16x32_bf16(ah, bh, acc[w][ft], 0, 0, 0);
        acc[w][ft] = __builtin_amdgcn_mfma_f32_16x16x32_bf16(ah, bl, acc[w][ft], 0, 0, 0);
      }
  }

#pragma unroll
  for (int ft = 0; ft < NF; ++ft) {
    int col = ft * 16 + r;
    if (col < F) {
      float bv = bias2[col];
#pragma unroll
      for (int i = 0; i < 4; ++i) {
        int row = row0 + q * 4 + i;
        if (row < N) {
          OUT1[(size_t)row * F + col] = rne16(acc[0][ft][i]);
          OUT2[(size_t)row * F + col] = rne16(acc[1][ft][i] + bv);
        }
      }
    }
  }
}

// ---------------- final: MFMA GEMM (K=96, F=40) + fused log-softmax
__global__ __launch_bounds__(256, 4) void final_mfma_kernel(
    const uint16_t* __restrict__ XB96,
    const uint16_t* __restrict__ Wh, const uint16_t* __restrict__ Wl,
    const float* __restrict__ lpb, float* __restrict__ out, int N) {
  constexpr int K = 96, F = 40, FP = 48, NF = 3, RS = 40;
  __shared__ short sW[2][FP][RS];

  int tid  = threadIdx.x;
  int wave = tid >> 6, lane = tid & 63;
  int r = lane & 15, q = lane >> 4;
  int row0 = blockIdx.x * 64 + wave * 16;
  int rowA = row0 + r; if (rowA > N - 1) rowA = N - 1;
  int srow = tid >> 2, sj = tid & 3;

  v4f acc[NF];
#pragma unroll
  for (int i = 0; i < NF; ++i) acc[i] = (v4f){0.f, 0.f, 0.f, 0.f};

  for (int c = 0; c < 3; ++c) {
    int kc = c * 32;
    if (c) __syncthreads();
    if (srow < FP) {
      const v8s zz = {0, 0, 0, 0, 0, 0, 0, 0};
      v8s hv = zz, lv = zz;
      if (srow < F) {
        hv = *reinterpret_cast<const v8s*>(Wh + (size_t)srow * K + kc + sj * 8);
        lv = *reinterpret_cast<const v8s*>(Wl + (size_t)srow * K + kc + sj * 8);
      }
      *reinterpret_cast<v8s*>(&sW[0][srow][sj * 8]) = hv;
      *reinterpret_cast<v8s*>(&sW[1][srow][sj * 8]) = lv;
    }
    v8s ah = *reinterpret_cast<const v8s*>(XB96 + (size_t)rowA * K + kc + q * 8);
    __syncthreads();
#pragma unroll
    for (int ft = 0; ft < NF; ++ft) {
      v8s bh = *reinterpret_cast<const v8s*>(&sW[0][ft * 16 + r][q * 8]);
      v8s bl = *reinterpret_cast<const v8s*>(&sW[1][ft * 16 + r][q * 8]);
      acc[ft] = __builtin_amdgcn_mfma_f32_16x16x32_bf16(ah, bh, acc[ft], 0, 0, 0);
      acc[ft] = __builtin_amdgcn_mfma_f32_16x16x32_bf16(ah, bl, acc[ft], 0, 0, 0);
    }
  }

  float b0 = lpb[r], b1 = lpb[16 + r];
  float b2 = (r < 8) ? lpb[32 + r] : 0.f;
#pragma unroll
  for (int i = 0; i < 4; ++i) {
    int row = row0 + q * 4 + i;
    float l0 = acc[0][i] + b0;
    float l1 = acc[1][i] + b1;
    float l2 = (r < 8) ? (acc[2][i] + b2) : -1e30f;
    float m = fmaxf(fmaxf(l0, l1), l2);
#pragma unroll
    for (int d = 1; d < 16; d <<= 1) m = fmaxf(m, __shfl_xor(m, d));
    float e = __expf(l0 - m) + __expf(l1 - m) + ((r < 8) ? __expf(l2 - m) : 0.f);
#pragma unroll
    for (int d = 1; d < 16; d <<= 1) e += __shfl_xor(e, d);
    if (row < N) {
      float ls = m + __logf(e);
      out[(size_t)row * 40 + r]      = l0 - ls;
      out[(size_t)row * 40 + 16 + r] = l1 - ls;
      if (r < 8) out[(size_t)row * 40 + 32 + r] = l2 - ls;
    }
  }
}

// ---------------------------------------------------------------- launcher
extern "C" void kernel_launch(void* const* d_in, const int* in_sizes, int n_in,
                              void* d_out, int out_size, void* d_ws, size_t ws_size,
                              hipStream_t stream) {
  const float* x      = (const float*)d_in[0];
  const int* src      = (const int*)d_in[1];
  const int* dst      = (const int*)d_in[2];
  const int* he_node  = (const int*)d_in[3];
  const int* he_edge  = (const int*)d_in[4];
  const float* s0wl = (const float*)d_in[5],  *s0wr = (const float*)d_in[6],  *s0b = (const float*)d_in[7];
  const float* s1wl = (const float*)d_in[8],  *s1wr = (const float*)d_in[9],  *s1b = (const float*)d_in[10];
  const float* s2wl = (const float*)d_in[11], *s2wr = (const float*)d_in[12], *s2b = (const float*)d_in[13];
  const float* h0w = (const float*)d_in[14], *h0b = (const float*)d_in[15];
  const float* h1w = (const float*)d_in[16], *h1b = (const float*)d_in[17];
  const float* h2w = (const float*)d_in[18], *h2b = (const float*)d_in[19];
  const float* h3w = (const float*)d_in[20], *h3b = (const float*)d_in[21];
  const float* h4w = (const float*)d_in[22], *h4b = (const float*)d_in[23];
  const float* lpw = (const float*)d_in[24], *lpb = (const float*)d_in[25];
  float* out = (float*)d_out;

  char* p = (char*)d_ws;
  auto carve = [&](size_t bytes) -> char* {
    char* r = p;
    p += (bytes + 255) & ~(size_t)255;
    return r;
  };
  int* adj_off  = (int*)carve((size_t)(N_NODES + 1) * 4);
  uint16_t* adj_src  = (uint16_t*)carve((size_t)N_EDGE * 2);
  int* heg_off  = (int*)carve((size_t)(N_HE + 1) * 4);
  uint16_t* heg_node = (uint16_t*)carve((size_t)N_INC * 2);
  int* hng_off  = (int*)carve((size_t)(N_NODES + 1) * 4);
  uint16_t* hng_edge = (uint16_t*)carve((size_t)N_INC * 2);
  int* gcnt     = (int*)carve((size_t)NBREL * 4);
  int* brel     = (int*)carve((size_t)NBREL * 4);
  int* gbb      = (int*)carve((size_t)278 * 4);
  uint32_t* stg_adj = (uint32_t*)carve((size_t)N_EDGE * 4);
  uint32_t* stg_heg = (uint32_t*)carve((size_t)N_INC * 4);
  uint32_t* stg_hng = (uint32_t*)carve((size_t)N_INC * 4);
  float* deg_inv = (float*)carve((size_t)N_NODES * 4);
  float* binv    = (float*)carve((size_t)N_HE * 4);
  float* dinv    = (float*)carve((size_t)N_NODES * 4);
  uint16_t* Wh = (uint16_t*)carve((size_t)W_TOTAL * 2);
  uint16_t* Wl = (uint16_t*)carve((size_t)W_TOTAL * 2);
  uint16_t* lpWh = (uint16_t*)carve((size_t)40 * 96 * 2);
  uint16_t* lpWl = (uint16_t*)carve((size_t)40 * 96 * 2);
  uint16_t* XB = (uint16_t*)carve((size_t)N_NODES * 128 * 2);
  uint16_t* U  = (uint16_t*)carve((size_t)N_NODES * 128 * 2);
  uint16_t* NA = (uint16_t*)carve((size_t)N_NODES * 256 * 2);
  uint16_t* NB_ = (uint16_t*)carve((size_t)N_NODES * 256 * 2);
  uint16_t* NC = (uint16_t*)carve((size_t)N_NODES * 256 * 2);
  uint16_t* EFa = (uint16_t*)carve((size_t)N_HE * 256 * 2);
  uint16_t* EFb = (uint16_t*)carve((size_t)N_HE * 256 * 2);
  uint16_t* T40 = (uint16_t*)carve((size_t)N_NODES * 40 * 2);
  uint16_t* T40B = (uint16_t*)carve((size_t)N_NODES * 40 * 2);
  uint16_t* T40H = (uint16_t*)carve((size_t)N_NODES * 40 * 2);
  uint16_t* XCATB = (uint16_t*)carve((size_t)N_NODES * 96 * 2);

  const int GL = (N_NODES + 63) / 64;              // F=40 row-strip grid
  const int GB = ((N_NODES + 127) / 128) * 2;      // 391*2 = 782, 256-thr
  const int GH = ((N_HE + 31) / 32) * 2;           // 157*2 = 314, 64-thr

  // ---- prep (zero + weight split + lpw split + x cvt) and binned CSR build
  prep_kernel<<<8052, 256, 0, stream>>>(gcnt, brel,
                                        s0wl, s0wr, s1wl, s1wr, s2wl, s2wr,
                                        h0w, h1w, h2w, h3w, h4w, Wh, Wl,
                                        lpw, lpWh, lpWl, x, XB);
  bhist_kernel<<<392, 256, 0, stream>>>(dst, he_edge, he_node, gcnt);
  bscan_kernel<<<1, 256, 0, stream>>>(gcnt, gbb, adj_off, heg_off, hng_off);
  binA_kernel<<<392, 256, 0, stream>>>(src, dst, he_node, he_edge,
                                       gbb, brel, stg_adj, stg_heg, stg_hng);
  binB2_kernel<<<275, 256, 0, stream>>>(gbb, stg_adj, stg_heg, stg_hng,
                                        adj_off, heg_off, hng_off,
                                        deg_inv, binv, dinv,
                                        adj_src, heg_node, hng_edge);

  // ---- merged layer-0 gathers (SAGE node-agg + hyper he-agg, both from XB)
  agg2b_kernel<128><<<N_NODES + N_HE, 64, 0, stream>>>(
      adj_off, adj_src, deg_inv, U, N_NODES,
      heg_off, heg_node, binv, EFa, XB);

  // ---- SAGE branch
  lin256_kernel<128, 128, 4><<<GB, 256, 0, stream>>>(
      U, Wh + 0, Wl + 0, XB, Wh + 32768, Wl + 32768, s0b, NA, 256, N_NODES, 1);
  aggb_kernel<256><<<N_NODES, 64, 0, stream>>>(adj_off, adj_src, deg_inv, NA, NB_, nullptr, 0);
  lin256_kernel<256, 256, 4><<<GB, 256, 0, stream>>>(
      NB_, Wh + 65536, Wl + 65536, NA, Wh + 131072, Wl + 131072, s1b, NC, 256, N_NODES, 1);
  lin40ab_kernel<<<GL, 256, 0, stream>>>(
      NC, Wh + 196608, Wl + 196608, Wh + 206848, Wl + 206848, s2b, T40, T40B, N_NODES);
  agg40s_kernel<<<N_NODES, 64, 0, stream>>>(adj_off, adj_src, deg_inv, T40, T40B, XCATB);

  // ---- Hypergraph branch: heagg -> tiny GEMM (5000 rows) -> nodeagg+bias+relu
  lin256_kernel<128, 0, 1><<<GH, 64, 0, stream>>>(
      EFa, Wh + 217088, Wl + 217088, nullptr, nullptr, nullptr, nullptr, EFb, 256, N_HE, 0);
  aggb_kernel<256><<<N_NODES, 64, 0, stream>>>(hng_off, hng_edge, dinv, EFb, NC, h0b, 1);

  aggb_kernel<256><<<N_HE, 64, 0, stream>>>(heg_off, heg_node, binv, NC, EFa, nullptr, 0);
  lin256_kernel<256, 0, 1><<<GH, 64, 0, stream>>>(
      EFa, Wh + 249856, Wl + 249856, nullptr, nullptr, nullptr, nullptr, EFb, 256, N_HE, 0);
  aggb_kernel<256><<<N_NODES, 64, 0, stream>>>(hng_off, hng_edge, dinv, EFb, NC, h1b, 1);

  aggb_kernel<256><<<N_HE, 64, 0, stream>>>(heg_off, heg_node, binv, NC, EFa, nullptr, 0);
  lin256_kernel<256, 0, 1><<<GH, 64, 0, stream>>>(
      EFa, Wh + 315392, Wl + 315392, nullptr, nullptr, nullptr, nullptr, EFb, 256, N_HE, 0);
  aggb_kernel<256><<<N_NODES, 64, 0, stream>>>(hng_off, hng_edge, dinv, EFb, NC, h2b, 1);

  aggb_kernel<256><<<N_HE, 64, 0, stream>>>(heg_off, heg_node, binv, NC, EFa, nullptr, 0);
  lin256_kernel<256, 0, 1><<<GH, 64, 0, stream>>>(
      EFa, Wh + 380928, Wl + 380928, nullptr, nullptr, nullptr, nullptr, EFb, 256, N_HE, 0);
  aggb_kernel<256><<<N_NODES, 64, 0, stream>>>(hng_off, hng_edge, dinv, EFb, NC, h3b, 1);

  // layer 4 (F=40): transform node features first, then two aggs
  lin2b_kernel<256, 0, 40, true><<<GL, 256, 0, stream>>>(
      NC, Wh + 446464, Wl + 446464, nullptr, nullptr, nullptr, nullptr, nullptr, T40H, 40, N_NODES, 0);
  aggb_kernel<40><<<N_HE, 64, 0, stream>>>(heg_off, heg_node, binv, T40H, EFa, nullptr, 0);
  agg40b_kernel<<<N_NODES, 64, 0, stream>>>(hng_off, hng_edge, dinv, EFa, h4b, XCATB);

  // ---- final MFMA linear + fused log_softmax
  final_mfma_kernel<<<GL, 256, 0, stream>>>(XCATB, lpWh, lpWl, lpb, out, N_NODES);
}

// Round 7
// 751.708 us; speedup vs baseline: 1.4023x; 1.0145x over previous
//
#include <hip/hip_runtime.h>
#include <hip/hip_bf16.h>
#include <cstdint>
#include <cstddef>

typedef __hip_bfloat16 bf16;
typedef short v8s __attribute__((ext_vector_type(8)));
typedef float v4f __attribute__((ext_vector_type(4)));
typedef unsigned short v8u __attribute__((ext_vector_type(8)));
typedef unsigned short v4u __attribute__((ext_vector_type(4)));
typedef unsigned short v2u __attribute__((ext_vector_type(2)));

#define N_NODES 50000
#define N_HE    5000
#define N_EDGE  800000
#define N_INC   400000
#define W_TOTAL 456704
#define NBREL   275   // 98 adj + 79 heg + 98 hng bucket cursors

#define AS1CV const __attribute__((address_space(1))) void*
#define AS3V  __attribute__((address_space(3))) void*

__device__ inline float bfh(uint32_t u) { return __uint_as_float(u << 16); }
__device__ inline uint16_t rne16(float f) {
  uint32_t u = __float_as_uint(f);
  return (uint16_t)((u + 0x7FFFu + ((u >> 16) & 1u)) >> 16);
}

// ---- prep: zero gcnt+brel + split weights (incl lpw, stride 96) + cvt x
// F=256 weight matrices are stored CHUNK-MAJOR + XOR-swizzled so that
// global_load_lds linear writes produce a bank-friendly LDS layout:
//   element w[row][c*32 + q*8 + e] -> idx c*8192 + row*32 + ((q^(row&3))<<3) + e
// F=40 matrices (s2wl/s2wr/h4w) stay row-major (old LDS path).
__global__ void prep_kernel(int* gcnt, int* brel,
                            const float* s0wl, const float* s0wr,
                            const float* s1wl, const float* s1wr,
                            const float* s2wl, const float* s2wr,
                            const float* h0w, const float* h1w,
                            const float* h2w, const float* h3w, const float* h4w,
                            uint16_t* hi, uint16_t* lo,
                            const float* lpw, uint16_t* lpWh, uint16_t* lpWl,
                            const float* X, uint16_t* XB) {
  int b = blockIdx.x;
  if (b < 3) {
    int i = b * 256 + threadIdx.x;
    if (i < NBREL) gcnt[i] = 0;
    else if (i < 2 * NBREL) brel[i - NBREL] = 0;
    return;
  }
  if (b < 1787) {
    int i = (b - 3) * 256 + threadIdx.x;
    if (i >= W_TOTAL) return;
    const float* src; int base; int kln2; int sw;
    if (i < 32768)       { src = s0wl; base = 0;      kln2 = 7; sw = 1; }
    else if (i < 65536)  { src = s0wr; base = 32768;  kln2 = 7; sw = 1; }
    else if (i < 131072) { src = s1wl; base = 65536;  kln2 = 8; sw = 1; }
    else if (i < 196608) { src = s1wr; base = 131072; kln2 = 8; sw = 1; }
    else if (i < 206848) { src = s2wl; base = 196608; kln2 = 8; sw = 0; }
    else if (i < 217088) { src = s2wr; base = 206848; kln2 = 8; sw = 0; }
    else if (i < 249856) { src = h0w;  base = 217088; kln2 = 7; sw = 1; }
    else if (i < 315392) { src = h1w;  base = 249856; kln2 = 8; sw = 1; }
    else if (i < 380928) { src = h2w;  base = 315392; kln2 = 8; sw = 1; }
    else if (i < 446464) { src = h3w;  base = 380928; kln2 = 8; sw = 1; }
    else                 { src = h4w;  base = 446464; kln2 = 8; sw = 0; }
    int j = i - base;
    float v = src[j];
    int nj = j;
    if (sw) {
      int row = j >> kln2;
      int col = j & ((1 << kln2) - 1);
      int c = col >> 5, qq = (col >> 3) & 3, e = col & 7;
      nj = c * 8192 + row * 32 + ((qq ^ (row & 3)) << 3) + e;
    }
    uint16_t hb = rne16(v);
    hi[base + nj] = hb;
    lo[base + nj] = rne16(v - bfh(hb));
    return;
  }
  if (b < 1802) {
    int i = (b - 1787) * 256 + threadIdx.x;   // 40 rows x 96 cols
    if (i >= 40 * 96) return;
    int row = i / 96, col = i - row * 96;
    float v = (col < 80) ? lpw[row * 80 + col] : 0.f;
    uint16_t hb = rne16(v);
    lpWh[i] = hb;
    lpWl[i] = rne16(v - bfh(hb));
    return;
  }
  {
    int i = (b - 1802) * 256 + threadIdx.x;   // v4 index
    if (i >= N_NODES * 32) return;
    v4f v = *((const v4f*)X + i);
    v4u o;
    o[0] = rne16(v[0]); o[1] = rne16(v[1]); o[2] = rne16(v[2]); o[3] = rne16(v[3]);
    *((v4u*)XB + i) = o;
  }
}

// ---------------- bucket-level histogram (LDS-local; replaces hist_kernel)
template <int NB, int SH>
__device__ inline void bhist_section(const int* __restrict__ key_arr, int n, int blk,
                                     int* __restrict__ gcnt) {
  __shared__ int h[128];
  int t = threadIdx.x;
  for (int k = t; k < NB; k += 256) h[k] = 0;
  __syncthreads();
  int e0 = blk * 4096;
  int cnt = min(4096, n - e0);
  for (int k = t; k < cnt; k += 256) atomicAdd(&h[key_arr[e0 + k] >> SH], 1);
  __syncthreads();
  for (int k = t; k < NB; k += 256) atomicAdd(&gcnt[k], h[k]);
}

__global__ __launch_bounds__(256) void bhist_kernel(
    const int* __restrict__ dst, const int* __restrict__ he_edge,
    const int* __restrict__ he_node, int* gcnt) {
  int b = blockIdx.x;
  if (b < 196)      bhist_section<98, 9>(dst, N_EDGE, b, gcnt);
  else if (b < 294) bhist_section<79, 6>(he_edge, N_INC, b - 196, gcnt + 98);
  else              bhist_section<98, 9>(he_node, N_INC, b - 294, gcnt + 177);
}

// ---------------- bucket-base scan (one wave per section) + CSR sentinels
__global__ void bscan_kernel(const int* __restrict__ gcnt, int* gbb,
                             int* adj_off, int* heg_off, int* hng_off) {
  int t = threadIdx.x;
  if (t == 0)        { int s = 0; for (int b = 0; b < 98; ++b) { gbb[b] = s; s += gcnt[b]; } gbb[98] = s; }
  else if (t == 64)  { int s = 0; for (int b = 0; b < 79; ++b) { gbb[99 + b] = s; s += gcnt[98 + b]; } gbb[99 + 79] = s; }
  else if (t == 128) { int s = 0; for (int b = 0; b < 98; ++b) { gbb[179 + b] = s; s += gcnt[177 + b]; } gbb[179 + 98] = s; }
  else if (t == 192) { adj_off[N_NODES] = N_EDGE; heg_off[N_HE] = N_INC; hng_off[N_NODES] = N_INC; }
}

// ---------------- binned two-phase fill (no scatter write amplification)
template <int NB, int SH>
__device__ inline void binA_section(const int* __restrict__ key_arr,
                                    const int* __restrict__ pay_arr, int n, int blk,
                                    const int* __restrict__ bb,
                                    int* brel, uint32_t* __restrict__ stg) {
  __shared__ int lcnt[128], lscan[128], lcnt2[128], gbase[128];
  __shared__ uint32_t sstage[4096];
  int t = threadIdx.x;
  int e0 = blk * 4096;
  int cnt = min(4096, n - e0);
  for (int k = t; k < NB; k += 256) { lcnt[k] = 0; lcnt2[k] = 0; }
  __syncthreads();
  for (int k = t; k < cnt; k += 256) atomicAdd(&lcnt[key_arr[e0 + k] >> SH], 1);
  __syncthreads();
  if (t == 0) {
    int s = 0;
    for (int b = 0; b < NB; ++b) { lscan[b] = s; s += lcnt[b]; }
  }
  __syncthreads();
  if (t < NB) gbase[t] = bb[t] + atomicAdd(&brel[t], lcnt[t]);
  __syncthreads();
  for (int k = t; k < cnt; k += 256) {
    int key = key_arr[e0 + k];
    int pay = pay_arr[e0 + k];
    int b = key >> SH;
    int r = atomicAdd(&lcnt2[b], 1);
    sstage[lscan[b] + r] = ((uint32_t)pay << 16) | (uint32_t)key;
  }
  __syncthreads();
  for (int b = 0; b < NB; ++b) {
    int len = lcnt[b], ls = lscan[b], gb = gbase[b];
    for (int k = t; k < len; k += 256) stg[gb + k] = sstage[ls + k];
  }
}

__global__ __launch_bounds__(256) void binA_kernel(
    const int* __restrict__ src, const int* __restrict__ dst,
    const int* __restrict__ he_node, const int* __restrict__ he_edge,
    const int* __restrict__ gbb, int* brel,
    uint32_t* stg_adj, uint32_t* stg_heg, uint32_t* stg_hng) {
  int b = blockIdx.x;
  if (b < 196)      binA_section<98, 9>(dst, src, N_EDGE, b, gbb, brel, stg_adj);
  else if (b < 294) binA_section<79, 6>(he_edge, he_node, N_INC, b - 196, gbb + 99, brel + 98, stg_heg);
  else              binA_section<98, 9>(he_node, he_edge, N_INC, b - 294, gbb + 179, brel + 177, stg_hng);
}

// Pass B + per-node count/scan: writes CSR offsets, reciprocal scales, payloads.
template <int BS, int SH, int MODE>
__device__ inline void binB2_section(int bkt, const int* __restrict__ bb, int nkeys,
                                     const uint32_t* __restrict__ stg,
                                     int* __restrict__ off_out,
                                     float* __restrict__ scl,
                                     uint16_t* __restrict__ out) {
  __shared__ int lcnt[512], loff[512], lcur[512];
  __shared__ int ws[4];
  int t = threadIdx.x;
  int nb0 = bkt << SH;
  int nb1 = min(nb0 + BS, nkeys);
  int nn = nb1 - nb0;
  int e0 = bb[bkt], e1 = bb[bkt + 1];
  for (int k = t; k < nn; k += 256) lcnt[k] = 0;
  __syncthreads();
  for (int e = e0 + t; e < e1; e += 256)
    atomicAdd(&lcnt[(int)(stg[e] & 0xFFFFu) - nb0], 1);
  __syncthreads();
  // exclusive scan over nn counts (2 per thread, shfl within wave, 4 waves)
  int lane = t & 63, wv = t >> 6;
  int i0 = 2 * t;
  int a0 = (i0 < nn) ? lcnt[i0] : 0;
  int a1 = (i0 + 1 < nn) ? lcnt[i0 + 1] : 0;
  int ts = a0 + a1;
  int val = ts;
#pragma unroll
  for (int d = 1; d < 64; d <<= 1) {
    int x = __shfl_up(val, d);
    if (lane >= d) val += x;
  }
  if (lane == 63) ws[wv] = val;
  __syncthreads();
  if (t == 0) {
    int s = 0;
#pragma unroll
    for (int w = 0; w < 4; ++w) { int v = ws[w]; ws[w] = s; s += v; }
  }
  __syncthreads();
  int excl = ws[wv] + (val - ts);
  if (i0 < nn) loff[i0] = excl;
  if (i0 + 1 < nn) loff[i0 + 1] = excl + a0;
  __syncthreads();
  for (int k = t; k < nn; k += 256) {
    int base = e0 + loff[k];
    off_out[nb0 + k] = base;
    lcur[k] = base;
    int c = lcnt[k];
    scl[nb0 + k] = (MODE == 0) ? 1.0f / (float)(c > 1 ? c : 1)
                               : (c > 0 ? 1.0f / (float)c : 0.f);
  }
  __syncthreads();
  for (int e = e0 + t; e < e1; e += 256) {
    uint32_t v = stg[e];
    int key = (int)(v & 0xFFFFu);
    int p = atomicAdd(&lcur[key - nb0], 1);
    out[p] = (uint16_t)(v >> 16);
  }
}

__global__ __launch_bounds__(256) void binB2_kernel(
    const int* __restrict__ gbb,
    const uint32_t* __restrict__ stg_adj, const uint32_t* __restrict__ stg_heg,
    const uint32_t* __restrict__ stg_hng,
    int* adj_off, int* heg_off, int* hng_off,
    float* deg_inv, float* binv, float* dinv,
    uint16_t* adj_src, uint16_t* heg_node, uint16_t* hng_edge) {
  int b = blockIdx.x;
  if (b < 98)       binB2_section<512, 9, 0>(b, gbb, N_NODES, stg_adj, adj_off, deg_inv, adj_src);
  else if (b < 177) binB2_section<64, 6, 1>(b - 98, gbb + 99, N_HE, stg_heg, heg_off, binv, heg_node);
  else              binB2_section<512, 9, 1>(b - 177, gbb + 179, N_NODES, stg_hng, hng_off, dinv, hng_edge);
}

// ------------------------------- gather-mean row body (uint16 CSR idx)
template <int F>
__device__ inline void agg_row(const int* __restrict__ off, const uint16_t* __restrict__ idx,
                               const float* __restrict__ scale,
                               const uint16_t* __restrict__ X,
                               uint16_t* __restrict__ OUT, int row,
                               const float* __restrict__ bias, int do_relu) {
  constexpr int VEC = (F >= 256) ? 4 : 2;
  int t = threadIdx.x;
  if (t * VEC >= F) return;
  int j0 = off[row], j1 = off[row + 1];
  float sc = scale[row];
  float acc[VEC];
#pragma unroll
  for (int k = 0; k < VEC; ++k) acc[k] = 0.f;

  int j = j0;
  for (; j + 7 < j1; j += 8) {
    int s[8];
#pragma unroll
    for (int u = 0; u < 8; ++u) s[u] = idx[j + u];
    if (VEC == 4) {
      v4u v[8];
#pragma unroll
      for (int u = 0; u < 8; ++u) v[u] = *(const v4u*)(X + (size_t)s[u] * F + t * 4);
#pragma unroll
      for (int u = 0; u < 8; ++u)
#pragma unroll
        for (int k = 0; k < 4; ++k) acc[k] += bfh(v[u][k]);
    } else {
      v2u v[8];
#pragma unroll
      for (int u = 0; u < 8; ++u) v[u] = *(const v2u*)(X + (size_t)s[u] * F + t * 2);
#pragma unroll
      for (int u = 0; u < 8; ++u)
#pragma unroll
        for (int k = 0; k < 2; ++k) acc[k] += bfh(v[u][k]);
    }
  }
  for (; j < j1; ++j) {
    int s = idx[j];
    if (VEC == 4) {
      v4u a = *(const v4u*)(X + (size_t)s * F + t * 4);
#pragma unroll
      for (int k = 0; k < 4; ++k) acc[k] += bfh(a[k]);
    } else {
      v2u a = *(const v2u*)(X + (size_t)s * F + t * 2);
#pragma unroll
      for (int k = 0; k < 2; ++k) acc[k] += bfh(a[k]);
    }
  }

  if (VEC == 4) {
    v4u o;
#pragma unroll
    for (int k = 0; k < 4; ++k) {
      float v = acc[k] * sc;
      if (bias) { v += bias[t * 4 + k]; if (do_relu) v = fmaxf(v, 0.f); }
      o[k] = rne16(v);
    }
    *(v4u*)(OUT + (size_t)row * F + t * 4) = o;
  } else {
    v2u o;
#pragma unroll
    for (int k = 0; k < 2; ++k) {
      float v = acc[k] * sc;
      if (bias) { v += bias[t * 2 + k]; if (do_relu) v = fmaxf(v, 0.f); }
      o[k] = rne16(v);
    }
    *(v2u*)(OUT + (size_t)row * F + t * 2) = o;
  }
}

template <int F>
__global__ void aggb_kernel(const int* __restrict__ off, const uint16_t* __restrict__ idx,
                            const float* __restrict__ scale,
                            const uint16_t* __restrict__ X,
                            uint16_t* __restrict__ OUT,
                            const float* __restrict__ bias, int do_relu) {
  agg_row<F>(off, idx, scale, X, OUT, blockIdx.x, bias, do_relu);
}

template <int F>
__global__ void agg2b_kernel(const int* __restrict__ off1, const uint16_t* __restrict__ idx1,
                             const float* __restrict__ sc1, uint16_t* __restrict__ OUT1, int n1,
                             const int* __restrict__ off2, const uint16_t* __restrict__ idx2,
                             const float* __restrict__ sc2, uint16_t* __restrict__ OUT2,
                             const uint16_t* __restrict__ X) {
  int row = blockIdx.x;
  if (row < n1) agg_row<F>(off1, idx1, sc1, X, OUT1, row, nullptr, 0);
  else          agg_row<F>(off2, idx2, sc2, X, OUT2, row - n1, nullptr, 0);
}

// Hyper tail: XCATB[:,40:80] = bf16(dinv*agg(EF40) + bias); zeros pad 80:96.
// 8-wide edge batching (agg_row pattern) for memory-level parallelism.
__global__ void agg40b_kernel(const int* __restrict__ off, const uint16_t* __restrict__ idx,
                              const float* __restrict__ scale,
                              const uint16_t* __restrict__ EF40,
                              const float* __restrict__ bias,
                              uint16_t* __restrict__ XCATB) {
  int row = blockIdx.x;
  int t = threadIdx.x;
  if (t < 8) {
    v2u z = {0, 0};
    *(v2u*)(XCATB + (size_t)row * 96 + 80 + t * 2) = z;
  }
  if (t >= 20) return;
  int j0 = off[row], j1 = off[row + 1];
  float sc = scale[row];
  float a0 = 0.f, a1 = 0.f;
  int j = j0;
  for (; j + 7 < j1; j += 8) {
    int s[8];
#pragma unroll
    for (int u = 0; u < 8; ++u) s[u] = idx[j + u];
    v2u v[8];
#pragma unroll
    for (int u = 0; u < 8; ++u) v[u] = *(const v2u*)(EF40 + (size_t)s[u] * 40 + t * 2);
#pragma unroll
    for (int u = 0; u < 8; ++u) { a0 += bfh(v[u][0]); a1 += bfh(v[u][1]); }
  }
  for (; j < j1; ++j) {
    int s = idx[j];
    v2u v = *(const v2u*)(EF40 + (size_t)s * 40 + t * 2);
    a0 += bfh(v[0]);
    a1 += bfh(v[1]);
  }
  v2u o;
  o[0] = rne16(a0 * sc + bias[t * 2]);
  o[1] = rne16(a1 * sc + bias[t * 2 + 1]);
  *(v2u*)(XCATB + (size_t)row * 96 + 40 + t * 2) = o;
}

// SAGE tail: XCATB[:, :40] = bf16(deg_inv*agg(T40a) + T40b)
// 8-wide edge batching (agg_row pattern) for memory-level parallelism.
__global__ void agg40s_kernel(const int* __restrict__ off, const uint16_t* __restrict__ idx,
                              const float* __restrict__ scale,
                              const uint16_t* __restrict__ T40a,
                              const uint16_t* __restrict__ T40b,
                              uint16_t* __restrict__ XCATB) {
  int row = blockIdx.x;
  int t = threadIdx.x;
  if (t >= 20) return;
  int j0 = off[row], j1 = off[row + 1];
  float sc = scale[row];
  float a0 = 0.f, a1 = 0.f;
  int j = j0;
  for (; j + 7 < j1; j += 8) {
    int s[8];
#pragma unroll
    for (int u = 0; u < 8; ++u) s[u] = idx[j + u];
    v2u v[8];
#pragma unroll
    for (int u = 0; u < 8; ++u) v[u] = *(const v2u*)(T40a + (size_t)s[u] * 40 + t * 2);
#pragma unroll
    for (int u = 0; u < 8; ++u) { a0 += bfh(v[u][0]); a1 += bfh(v[u][1]); }
  }
  for (; j < j1; ++j) {
    int s = idx[j];
    v2u v = *(const v2u*)(T40a + (size_t)s * 40 + t * 2);
    a0 += bfh(v[0]);
    a1 += bfh(v[1]);
  }
  v2u b = *(const v2u*)(T40b + (size_t)row * 40 + t * 2);
  v2u o;
  o[0] = rne16(a0 * sc + bfh(b[0]));
  o[1] = rne16(a1 * sc + bfh(b[1]));
  *(v2u*)(XCATB + (size_t)row * 96 + t * 2) = o;
}

// ------------------------------------- pipelined F=256 MFMA GEMM (T3+T4)
// 3-buffer LDS + 3-slot A-register ring, BOTH prefetched 2 chunks ahead:
// per chunk c, wait vmcnt(2*PPW+2) (counted: retires exactly A_c + S_c),
// barrier, issue loadA(c+2)+stageC(c+2), then ds_read+MFMA chunk c.
// A cover = 2 chunk bodies (~1536 cyc) > HBM latency (~900) -> no A stall.
template <int N_>
__device__ __forceinline__ void vwait() {
  if constexpr (N_ == 0)       asm volatile("s_waitcnt vmcnt(0)" ::: "memory");
  else if constexpr (N_ == 6)  asm volatile("s_waitcnt vmcnt(6)" ::: "memory");
  else if constexpr (N_ == 18) asm volatile("s_waitcnt vmcnt(18)" ::: "memory");
}

template <int K1, int K2, int WAVES>
__global__ __launch_bounds__(WAVES * 64, 3) void lin256_kernel(
    const uint16_t* __restrict__ X1, const uint16_t* __restrict__ W1h, const uint16_t* __restrict__ W1l,
    const uint16_t* __restrict__ X2, const uint16_t* __restrict__ W2h, const uint16_t* __restrict__ W2l,
    const float* __restrict__ bias, uint16_t* __restrict__ OUT,
    int out_ld, int N, int do_relu) {
  constexpr int NC1 = K1 / 32;
  constexpr int NC2 = (K2 > 0) ? K2 / 32 : 0;
  constexpr int NCH = NC1 + NC2;
  constexpr int PPW = 8 / WAVES;     // 1KB staging units per wave per array
  constexpr int GW  = 2 * PPW + 2;   // mid-loop vmcnt: leaves A_{c+1}+S_{c+1}
  __shared__ short sW[3][2][128][32];   // 48 KB: [buf][hi/lo][wrow][kcol-swz]

  int tid  = threadIdx.x;
  int wave = tid >> 6, lane = tid & 63;
  int r = lane & 15, q = lane >> 4;
  int ct = blockIdx.x & 1, rt = blockIdx.x >> 1;
  int wr0 = rt * (WAVES * 32) + wave * 32;
  int colbase = ct << 7;
  int colsw = (q ^ (r & 3)) << 3;
  int rw0 = min(wr0 + r, N - 1);
  int rw1 = min(wr0 + 16 + r, N - 1);

  v8s aT[3][2];
  v4f acc[2][8];
#pragma unroll
  for (int g = 0; g < 2; ++g)
#pragma unroll
    for (int f = 0; f < 8; ++f) acc[g][f] = (v4f){0.f, 0.f, 0.f, 0.f};

  auto loadAinto = [&](int cc, v8s& d0, v8s& d1) {
    const uint16_t* Xs = (K2 == 0 || cc < NC1) ? X1 : X2;
    const int Ks = (K2 == 0 || cc < NC1) ? K1 : K2;
    const int kk = (K2 == 0 || cc < NC1) ? cc : cc - NC1;
    d0 = *reinterpret_cast<const v8s*>(Xs + (size_t)rw0 * Ks + kk * 32 + q * 8);
    d1 = *reinterpret_cast<const v8s*>(Xs + (size_t)rw1 * Ks + kk * 32 + q * 8);
  };
  auto stageC = [&](int cn) {
    const uint16_t* bh = (K2 == 0 || cn < NC1)
        ? (W1h + (size_t)cn * 8192) : (W2h + (size_t)(cn - NC1) * 8192);
    const uint16_t* bl = (K2 == 0 || cn < NC1)
        ? (W1l + (size_t)cn * 8192) : (W2l + (size_t)(cn - NC1) * 8192);
    bh += colbase * 32 + lane * 8;
    bl += colbase * 32 + lane * 8;
    short* d = &sW[cn % 3][0][0][0];
#pragma unroll
    for (int pp = 0; pp < PPW; ++pp) {
      int p = wave + pp * WAVES;
      __builtin_amdgcn_global_load_lds((AS1CV)(bh + p * 512), (AS3V)(d + p * 512), 16, 0, 0);
      __builtin_amdgcn_global_load_lds((AS1CV)(bl + p * 512), (AS3V)(d + 4096 + p * 512), 16, 0, 0);
    }
  };

  // prologue order A0,S0,A1,S1 so vwait<GW> retires exactly A_c+S_c each iter
  loadAinto(0, aT[0][0], aT[0][1]);
  stageC(0);
  loadAinto(1, aT[1][0], aT[1][1]);
  stageC(1);

#pragma unroll
  for (int c = 0; c < NCH; ++c) {
    if (c < NCH - 1) vwait<GW>(); else vwait<0>();
    __builtin_amdgcn_s_barrier();
    asm volatile("" ::: "memory");
    __builtin_amdgcn_sched_barrier(0);
    if (c + 2 < NCH) {
      loadAinto(c + 2, aT[(c + 2) % 3][0], aT[(c + 2) % 3][1]);
      stageC(c + 2);
    }
    const short* bb = &sW[c % 3][0][0][0];
#pragma unroll
    for (int ft = 0; ft < 8; ++ft) {
      v8s bh = *reinterpret_cast<const v8s*>(bb + (ft * 16 + r) * 32 + colsw);
      v8s bl = *reinterpret_cast<const v8s*>(bb + 4096 + (ft * 16 + r) * 32 + colsw);
      acc[0][ft] = __builtin_amdgcn_mfma_f32_16x16x32_bf16(aT[c % 3][0], bh, acc[0][ft], 0, 0, 0);
      acc[0][ft] = __builtin_amdgcn_mfma_f32_16x16x32_bf16(aT[c % 3][0], bl, acc[0][ft], 0, 0, 0);
      acc[1][ft] = __builtin_amdgcn_mfma_f32_16x16x32_bf16(aT[c % 3][1], bh, acc[1][ft], 0, 0, 0);
      acc[1][ft] = __builtin_amdgcn_mfma_f32_16x16x32_bf16(aT[c % 3][1], bl, acc[1][ft], 0, 0, 0);
    }
  }

#pragma unroll
  for (int g = 0; g < 2; ++g)
#pragma unroll
    for (int ft = 0; ft < 8; ++ft) {
      int col = colbase + ft * 16 + r;
      float bv = bias ? bias[col] : 0.f;
#pragma unroll
      for (int i = 0; i < 4; ++i) {
        int row = wr0 + g * 16 + q * 4 + i;
        if (row < N) {
          float v = acc[g][ft][i] + bv;
          if (do_relu) v = fmaxf(v, 0.f);
          OUT[(size_t)row * out_ld + col] = rne16(v);
        }
      }
    }
}

// ------------------------------------- F=40 LDS row-strip GEMM (proven path)
template <int K1, int K2, int F, bool OUTBF>
__global__ __launch_bounds__(256, 4) void lin2b_kernel(
    const uint16_t* __restrict__ X1, const uint16_t* __restrict__ W1h, const uint16_t* __restrict__ W1l,
    const uint16_t* __restrict__ X2, const uint16_t* __restrict__ W2h, const uint16_t* __restrict__ W2l,
    const float* __restrict__ bias, const uint16_t* __restrict__ addin,
    void* __restrict__ OUTP, int out_ld, int N, int do_relu) {
  constexpr int FP  = (F + 15) & ~15;
  constexpr int NF  = FP / 16;
  constexpr int NC1 = K1 / 32;
  constexpr int NCH = (K1 + (K2 > 0 ? K2 : 0)) / 32;
  constexpr int RS  = 40;
  __shared__ short sW[2][FP][RS];

  int tid  = threadIdx.x;
  int wave = tid >> 6, lane = tid & 63;
  int r = lane & 15, q = lane >> 4;
  int row0 = blockIdx.x * 64 + wave * 16;
  int rowA = row0 + r; if (rowA > N - 1) rowA = N - 1;

  int srow = tid >> 2;
  int sj   = tid & 3;

  v4f acc[NF];
#pragma unroll
  for (int i = 0; i < NF; ++i) acc[i] = (v4f){0.f, 0.f, 0.f, 0.f};

  for (int c = 0; c < NCH; ++c) {
    const bool first = (K2 == 0) || (c < NC1);
    const uint16_t* Wh = first ? W1h : W2h;
    const uint16_t* Wl = first ? W1l : W2l;
    const uint16_t* Xs = first ? X1 : X2;
    const int K  = first ? K1 : K2;
    const int kc = (first ? c : c - NC1) * 32;

    if (c) __syncthreads();
    const v8s zz = {0, 0, 0, 0, 0, 0, 0, 0};
#pragma unroll
    for (int pass = 0; pass < (FP + 63) / 64; ++pass) {
      int row = srow + pass * 64;
      if (row < FP) {
        v8s hv = zz, lv = zz;
        if (row < F) {
          hv = *reinterpret_cast<const v8s*>(Wh + (size_t)row * K + kc + sj * 8);
          lv = *reinterpret_cast<const v8s*>(Wl + (size_t)row * K + kc + sj * 8);
        }
        *reinterpret_cast<v8s*>(&sW[0][row][sj * 8]) = hv;
        *reinterpret_cast<v8s*>(&sW[1][row][sj * 8]) = lv;
      }
    }
    v8s ah = *reinterpret_cast<const v8s*>(Xs + (size_t)rowA * K + kc + q * 8);
    __syncthreads();
#pragma unroll
    for (int ft = 0; ft < NF; ++ft) {
      v8s bh = *reinterpret_cast<const v8s*>(&sW[0][ft * 16 + r][q * 8]);
      v8s bl = *reinterpret_cast<const v8s*>(&sW[1][ft * 16 + r][q * 8]);
      acc[ft] = __builtin_amdgcn_mfma_f32_16x16x32_bf16(ah, bh, acc[ft], 0, 0, 0);
      acc[ft] = __builtin_amdgcn_mfma_f32_16x16x32_bf16(ah, bl, acc[ft], 0, 0, 0);
    }
  }

#pragma unroll
  for (int ft = 0; ft < NF; ++ft) {
    int col = ft * 16 + r;
    if (col < F) {
      float bv = bias ? bias[col] : 0.f;
#pragma unroll
      for (int i = 0; i < 4; ++i) {
        int row = row0 + q * 4 + i;
        if (row < N) {
          float v = acc[ft][i] + bv;
          if (addin) v += bfh(addin[(size_t)row * F + col]);
          if (do_relu) v = fmaxf(v, 0.f);
          size_t o = (size_t)row * out_ld + col;
          if (OUTBF) ((uint16_t*)OUTP)[o] = rne16(v);
          else ((float*)OUTP)[o] = v;
        }
      }
    }
  }
}

// Dual-output 40-col GEMM (K=256): OUT1 = X*W1^T, OUT2 = X*W2^T + b2.
__global__ __launch_bounds__(256, 4) void lin40ab_kernel(
    const uint16_t* __restrict__ X,
    const uint16_t* __restrict__ W1h, const uint16_t* __restrict__ W1l,
    const uint16_t* __restrict__ W2h, const uint16_t* __restrict__ W2l,
    const float* __restrict__ bias2,
    uint16_t* __restrict__ OUT1, uint16_t* __restrict__ OUT2, int N) {
  constexpr int K = 256, F = 40, FP = 48, NF = 3, RS = 40;
  __shared__ short sW[2][2][FP][RS];

  int tid  = threadIdx.x;
  int wave = tid >> 6, lane = tid & 63;
  int r = lane & 15, q = lane >> 4;
  int row0 = blockIdx.x * 64 + wave * 16;
  int rowA = row0 + r; if (rowA > N - 1) rowA = N - 1;
  int srow = tid >> 2, sj = tid & 3;

  v4f acc[2][NF];
#pragma unroll
  for (int w = 0; w < 2; ++w)
#pragma unroll
    for (int i = 0; i < NF; ++i) acc[w][i] = (v4f){0.f, 0.f, 0.f, 0.f};

  for (int c = 0; c < K / 32; ++c) {
    int kc = c * 32;
    if (c) __syncthreads();
    if (srow < FP) {
      const v8s zz = {0, 0, 0, 0, 0, 0, 0, 0};
      v8s a = zz, b = zz, cc = zz, d = zz;
      if (srow < F) {
        a  = *reinterpret_cast<const v8s*>(W1h + (size_t)srow * K + kc + sj * 8);
        b  = *reinterpret_cast<const v8s*>(W1l + (size_t)srow * K + kc + sj * 8);
        cc = *reinterpret_cast<const v8s*>(W2h + (size_t)srow * K + kc + sj * 8);
        d  = *reinterpret_cast<const v8s*>(W2l + (size_t)srow * K + kc + sj * 8);
      }
      *reinterpret_cast<v8s*>(&sW[0][0][srow][sj * 8]) = a;
      *reinterpret_cast<v8s*>(&sW[0][1][srow][sj * 8]) = b;
      *reinterpret_cast<v8s*>(&sW[1][0][srow][sj * 8]) = cc;
      *reinterpret_cast<v8s*>(&sW[1][1][srow][sj * 8]) = d;
    }
    v8s ah = *reinterpret_cast<const v8s*>(X + (size_t)rowA * K + kc + q * 8);
    __syncthreads();
#pragma unroll
    for (int w = 0; w < 2; ++w)
#pragma unroll
      for (int ft = 0; ft < NF; ++ft) {
        v8s bh = *reinterpret_cast<const v8s*>(&sW[w][0][ft * 16 + r][q * 8]);
        v8s bl = *reinterpret_cast<const v8s*>(&sW[w][1][ft * 16 + r][q * 8]);
        acc[w][ft] = __builtin_amdgcn_mfma_f32_16x16x32_bf16(ah, bh, acc[w][ft], 0, 0, 0);
        acc[w][ft] = __builtin_amdgcn_mfma_f32_16x16x32_bf16(ah, bl, acc[w][ft], 0, 0, 0);
      }
  }

#pragma unroll
  for (int ft = 0; ft < NF; ++ft) {
    int col = ft * 16 + r;
    if (col < F) {
      float bv = bias2[col];
#pragma unroll
      for (int i = 0; i < 4; ++i) {
        int row = row0 + q * 4 + i;
        if (row < N) {
          OUT1[(size_t)row * F + col] = rne16(acc[0][ft][i]);
          OUT2[(size_t)row * F + col] = rne16(acc[1][ft][i] + bv);
        }
      }
    }
  }
}

// ---------------- final: MFMA GEMM (K=96, F=40) + fused log-softmax
__global__ __launch_bounds__(256, 4) void final_mfma_kernel(
    const uint16_t* __restrict__ XB96,
    const uint16_t* __restrict__ Wh, const uint16_t* __restrict__ Wl,
    const float* __restrict__ lpb, float* __restrict__ out, int N) {
  constexpr int K = 96, F = 40, FP = 48, NF = 3, RS = 40;
  __shared__ short sW[2][FP][RS];

  int tid  = threadIdx.x;
  int wave = tid >> 6, lane = tid & 63;
  int r = lane & 15, q = lane >> 4;
  int row0 = blockIdx.x * 64 + wave * 16;
  int rowA = row0 + r; if (rowA > N - 1) rowA = N - 1;
  int srow = tid >> 2, sj = tid & 3;

  v4f acc[NF];
#pragma unroll
  for (int i = 0; i < NF; ++i) acc[i] = (v4f){0.f, 0.f, 0.f, 0.f};

  for (int c = 0; c < 3; ++c) {
    int kc = c * 32;
    if (c) __syncthreads();
    if (srow < FP) {
      const v8s zz = {0, 0, 0, 0, 0, 0, 0, 0};
      v8s hv = zz, lv = zz;
      if (srow < F) {
        hv = *reinterpret_cast<const v8s*>(Wh + (size_t)srow * K + kc + sj * 8);
        lv = *reinterpret_cast<const v8s*>(Wl + (size_t)srow * K + kc + sj * 8);
      }
      *reinterpret_cast<v8s*>(&sW[0][srow][sj * 8]) = hv;
      *reinterpret_cast<v8s*>(&sW[1][srow][sj * 8]) = lv;
    }
    v8s ah = *reinterpret_cast<const v8s*>(XB96 + (size_t)rowA * K + kc + q * 8);
    __syncthreads();
#pragma unroll
    for (int ft = 0; ft < NF; ++ft) {
      v8s bh = *reinterpret_cast<const v8s*>(&sW[0][ft * 16 + r][q * 8]);
      v8s bl = *reinterpret_cast<const v8s*>(&sW[1][ft * 16 + r][q * 8]);
      acc[ft] = __builtin_amdgcn_mfma_f32_16x16x32_bf16(ah, bh, acc[ft], 0, 0, 0);
      acc[ft] = __builtin_amdgcn_mfma_f32_16x16x32_bf16(ah, bl, acc[ft], 0, 0, 0);
    }
  }

  float b0 = lpb[r], b1 = lpb[16 + r];
  float b2 = (r < 8) ? lpb[32 + r] : 0.f;
#pragma unroll
  for (int i = 0; i < 4; ++i) {
    int row = row0 + q * 4 + i;
    float l0 = acc[0][i] + b0;
    float l1 = acc[1][i] + b1;
    float l2 = (r < 8) ? (acc[2][i] + b2) : -1e30f;
    float m = fmaxf(fmaxf(l0, l1), l2);
#pragma unroll
    for (int d = 1; d < 16; d <<= 1) m = fmaxf(m, __shfl_xor(m, d));
    float e = __expf(l0 - m) + __expf(l1 - m) + ((r < 8) ? __expf(l2 - m) : 0.f);
#pragma unroll
    for (int d = 1; d < 16; d <<= 1) e += __shfl_xor(e, d);
    if (row < N) {
      float ls = m + __logf(e);
      out[(size_t)row * 40 + r]      = l0 - ls;
      out[(size_t)row * 40 + 16 + r] = l1 - ls;
      if (r < 8) out[(size_t)row * 40 + 32 + r] = l2 - ls;
    }
  }
}

// ---------------------------------------------------------------- launcher
extern "C" void kernel_launch(void* const* d_in, const int* in_sizes, int n_in,
                              void* d_out, int out_size, void* d_ws, size_t ws_size,
                              hipStream_t stream) {
  const float* x      = (const float*)d_in[0];
  const int* src      = (const int*)d_in[1];
  const int* dst      = (const int*)d_in[2];
  const int* he_node  = (const int*)d_in[3];
  const int* he_edge  = (const int*)d_in[4];
  const float* s0wl = (const float*)d_in[5],  *s0wr = (const float*)d_in[6],  *s0b = (const float*)d_in[7];
  const float* s1wl = (const float*)d_in[8],  *s1wr = (const float*)d_in[9],  *s1b = (const float*)d_in[10];
  const float* s2wl = (const float*)d_in[11], *s2wr = (const float*)d_in[12], *s2b = (const float*)d_in[13];
  const float* h0w = (const float*)d_in[14], *h0b = (const float*)d_in[15];
  const float* h1w = (const float*)d_in[16], *h1b = (const float*)d_in[17];
  const float* h2w = (const float*)d_in[18], *h2b = (const float*)d_in[19];
  const float* h3w = (const float*)d_in[20], *h3b = (const float*)d_in[21];
  const float* h4w = (const float*)d_in[22], *h4b = (const float*)d_in[23];
  const float* lpw = (const float*)d_in[24], *lpb = (const float*)d_in[25];
  float* out = (float*)d_out;

  char* p = (char*)d_ws;
  auto carve = [&](size_t bytes) -> char* {
    char* r = p;
    p += (bytes + 255) & ~(size_t)255;
    return r;
  };
  int* adj_off  = (int*)carve((size_t)(N_NODES + 1) * 4);
  uint16_t* adj_src  = (uint16_t*)carve((size_t)N_EDGE * 2);
  int* heg_off  = (int*)carve((size_t)(N_HE + 1) * 4);
  uint16_t* heg_node = (uint16_t*)carve((size_t)N_INC * 2);
  int* hng_off  = (int*)carve((size_t)(N_NODES + 1) * 4);
  uint16_t* hng_edge = (uint16_t*)carve((size_t)N_INC * 2);
  int* gcnt     = (int*)carve((size_t)NBREL * 4);
  int* brel     = (int*)carve((size_t)NBREL * 4);
  int* gbb      = (int*)carve((size_t)278 * 4);
  uint32_t* stg_adj = (uint32_t*)carve((size_t)N_EDGE * 4);
  uint32_t* stg_heg = (uint32_t*)carve((size_t)N_INC * 4);
  uint32_t* stg_hng = (uint32_t*)carve((size_t)N_INC * 4);
  float* deg_inv = (float*)carve((size_t)N_NODES * 4);
  float* binv    = (float*)carve((size_t)N_HE * 4);
  float* dinv    = (float*)carve((size_t)N_NODES * 4);
  uint16_t* Wh = (uint16_t*)carve((size_t)W_TOTAL * 2);
  uint16_t* Wl = (uint16_t*)carve((size_t)W_TOTAL * 2);
  uint16_t* lpWh = (uint16_t*)carve((size_t)40 * 96 * 2);
  uint16_t* lpWl = (uint16_t*)carve((size_t)40 * 96 * 2);
  uint16_t* XB = (uint16_t*)carve((size_t)N_NODES * 128 * 2);
  uint16_t* U  = (uint16_t*)carve((size_t)N_NODES * 128 * 2);
  uint16_t* NA = (uint16_t*)carve((size_t)N_NODES * 256 * 2);
  uint16_t* NB_ = (uint16_t*)carve((size_t)N_NODES * 256 * 2);
  uint16_t* NC = (uint16_t*)carve((size_t)N_NODES * 256 * 2);
  uint16_t* EFa = (uint16_t*)carve((size_t)N_HE * 256 * 2);
  uint16_t* EFb = (uint16_t*)carve((size_t)N_HE * 256 * 2);
  uint16_t* T40 = (uint16_t*)carve((size_t)N_NODES * 40 * 2);
  uint16_t* T40B = (uint16_t*)carve((size_t)N_NODES * 40 * 2);
  uint16_t* T40H = (uint16_t*)carve((size_t)N_NODES * 40 * 2);
  uint16_t* XCATB = (uint16_t*)carve((size_t)N_NODES * 96 * 2);

  const int GL = (N_NODES + 63) / 64;              // F=40 row-strip grid
  const int GB = ((N_NODES + 127) / 128) * 2;      // 391*2 = 782, 256-thr
  const int GH = ((N_HE + 31) / 32) * 2;           // 157*2 = 314, 64-thr

  // ---- prep (zero + weight split + lpw split + x cvt) and binned CSR build
  prep_kernel<<<8052, 256, 0, stream>>>(gcnt, brel,
                                        s0wl, s0wr, s1wl, s1wr, s2wl, s2wr,
                                        h0w, h1w, h2w, h3w, h4w, Wh, Wl,
                                        lpw, lpWh, lpWl, x, XB);
  bhist_kernel<<<392, 256, 0, stream>>>(dst, he_edge, he_node, gcnt);
  bscan_kernel<<<1, 256, 0, stream>>>(gcnt, gbb, adj_off, heg_off, hng_off);
  binA_kernel<<<392, 256, 0, stream>>>(src, dst, he_node, he_edge,
                                       gbb, brel, stg_adj, stg_heg, stg_hng);
  binB2_kernel<<<275, 256, 0, stream>>>(gbb, stg_adj, stg_heg, stg_hng,
                                        adj_off, heg_off, hng_off,
                                        deg_inv, binv, dinv,
                                        adj_src, heg_node, hng_edge);

  // ---- merged layer-0 gathers (SAGE node-agg + hyper he-agg, both from XB)
  agg2b_kernel<128><<<N_NODES + N_HE, 64, 0, stream>>>(
      adj_off, adj_src, deg_inv, U, N_NODES,
      heg_off, heg_node, binv, EFa, XB);

  // ---- SAGE branch
  lin256_kernel<128, 128, 4><<<GB, 256, 0, stream>>>(
      U, Wh + 0, Wl + 0, XB, Wh + 32768, Wl + 32768, s0b, NA, 256, N_NODES, 1);
  aggb_kernel<256><<<N_NODES, 64, 0, stream>>>(adj_off, adj_src, deg_inv, NA, NB_, nullptr, 0);
  lin256_kernel<256, 256, 4><<<GB, 256, 0, stream>>>(
      NB_, Wh + 65536, Wl + 65536, NA, Wh + 131072, Wl + 131072, s1b, NC, 256, N_NODES, 1);
  lin40ab_kernel<<<GL, 256, 0, stream>>>(
      NC, Wh + 196608, Wl + 196608, Wh + 206848, Wl + 206848, s2b, T40, T40B, N_NODES);
  agg40s_kernel<<<N_NODES, 64, 0, stream>>>(adj_off, adj_src, deg_inv, T40, T40B, XCATB);

  // ---- Hypergraph branch: heagg -> tiny GEMM (5000 rows) -> nodeagg+bias+relu
  lin256_kernel<128, 0, 1><<<GH, 64, 0, stream>>>(
      EFa, Wh + 217088, Wl + 217088, nullptr, nullptr, nullptr, nullptr, EFb, 256, N_HE, 0);
  aggb_kernel<256><<<N_NODES, 64, 0, stream>>>(hng_off, hng_edge, dinv, EFb, NC, h0b, 1);

  aggb_kernel<256><<<N_HE, 64, 0, stream>>>(heg_off, heg_node, binv, NC, EFa, nullptr, 0);
  lin256_kernel<256, 0, 1><<<GH, 64, 0, stream>>>(
      EFa, Wh + 249856, Wl + 249856, nullptr, nullptr, nullptr, nullptr, EFb, 256, N_HE, 0);
  aggb_kernel<256><<<N_NODES, 64, 0, stream>>>(hng_off, hng_edge, dinv, EFb, NC, h1b, 1);

  aggb_kernel<256><<<N_HE, 64, 0, stream>>>(heg_off, heg_node, binv, NC, EFa, nullptr, 0);
  lin256_kernel<256, 0, 1><<<GH, 64, 0, stream>>>(
      EFa, Wh + 315392, Wl + 315392, nullptr, nullptr, nullptr, nullptr, EFb, 256, N_HE, 0);
  aggb_kernel<256><<<N_NODES, 64, 0, stream>>>(hng_off, hng_edge, dinv, EFb, NC, h2b, 1);

  aggb_kernel<256><<<N_HE, 64, 0, stream>>>(heg_off, heg_node, binv, NC, EFa, nullptr, 0);
  lin256_kernel<256, 0, 1><<<GH, 64, 0, stream>>>(
      EFa, Wh + 380928, Wl + 380928, nullptr, nullptr, nullptr, nullptr, EFb, 256, N_HE, 0);
  aggb_kernel<256><<<N_NODES, 64, 0, stream>>>(hng_off, hng_edge, dinv, EFb, NC, h3b, 1);

  // layer 4 (F=40): transform node features first, then two aggs
  lin2b_kernel<256, 0, 40, true><<<GL, 256, 0, stream>>>(
      NC, Wh + 446464, Wl + 446464, nullptr, nullptr, nullptr, nullptr, nullptr, T40H, 40, N_NODES, 0);
  aggb_kernel<40><<<N_HE, 64, 0, stream>>>(heg_off, heg_node, binv, T40H, EFa, nullptr, 0);
  agg40b_kernel<<<N_NODES, 64, 0, stream>>>(hng_off, hng_edge, dinv, EFa, h4b, XCATB);

  // ---- final MFMA linear + fused log_softmax
  final_mfma_kernel<<<GL, 256, 0, stream>>>(XCATB, lpWh, lpWl, lpb, out, N_NODES);
}